// Round 1
// baseline (516.915 us; speedup 1.0000x reference)
//
#include <hip/hip_runtime.h>
#include <math.h>

// Problem constants (from reference): N=50000, E=800000, IN_DIM=256,
// H=4 heads, HID=32 (conv1 per-head), OUT=8 (conv2 per-head).
// HDIM1 = H*HID = 128, HDIM2 = H*OUT = 32.

// ---------------- CSR build ----------------

__global__ void count_deg_k(const int* __restrict__ dstA, int E, int ET,
                            int* __restrict__ deg) {
    int e = blockIdx.x * blockDim.x + threadIdx.x;
    if (e >= ET) return;
    int d = (e < E) ? dstA[e] : (e - E);   // self-loop edges appended
    atomicAdd(&deg[d], 1);
}

__global__ void scan_k(const int* __restrict__ deg, int* __restrict__ rowstart,
                       int n) {
    __shared__ int buf[1024];
    __shared__ int carry;
    if (threadIdx.x == 0) carry = 0;
    __syncthreads();
    for (int base = 0; base < n; base += 1024) {
        int i = base + (int)threadIdx.x;
        int v = (i < n) ? deg[i] : 0;
        buf[threadIdx.x] = v;
        __syncthreads();
        for (int off = 1; off < 1024; off <<= 1) {
            int t = (threadIdx.x >= (unsigned)off) ? buf[threadIdx.x - off] : 0;
            __syncthreads();
            buf[threadIdx.x] += t;
            __syncthreads();
        }
        if (i < n) rowstart[i] = carry + buf[threadIdx.x] - v;  // exclusive
        __syncthreads();
        if (threadIdx.x == 0) carry += buf[1023];
        __syncthreads();
    }
    if (threadIdx.x == 0) rowstart[n] = carry;
}

__global__ void scatter_k(const int* __restrict__ srcA, const int* __restrict__ dstA,
                          int E, int ET, const int* __restrict__ rowstart,
                          int* __restrict__ cursor, int* __restrict__ csrc) {
    int e = blockIdx.x * blockDim.x + threadIdx.x;
    if (e >= ET) return;
    int d, s;
    if (e < E) { d = dstA[e]; s = srcA[e]; } else { d = e - E; s = e - E; }
    int pos = atomicAdd(&cursor[d], 1);
    csrc[rowstart[d] + pos] = s;   // store SRC node id directly
}

// ---------------- GEMM1: [N,256] @ [256,128] ----------------

__global__ __launch_bounds__(256) void gemm1_k(const float* __restrict__ X,
                                               const float* __restrict__ W,
                                               float* __restrict__ H1, int n) {
    __shared__ float As[16][64];    // transposed: [k][m]
    __shared__ float Bs[16][128];   // [k][n]
    int tid = threadIdx.x;
    int tx = tid & 31;     // 32 col-groups of 4
    int ty = tid >> 5;     // 8 row-groups of 8
    int brow = blockIdx.x * 64;
    float acc[8][4];
#pragma unroll
    for (int i = 0; i < 8; ++i)
#pragma unroll
        for (int j = 0; j < 4; ++j) acc[i][j] = 0.f;

    for (int k0 = 0; k0 < 256; k0 += 16) {
        {   // stage A tile (64 rows x 16 k), transposed into LDS
            int r = tid >> 2, kq = (tid & 3) * 4;
            int gr = brow + r;
            float4 av = (gr < n) ? *(const float4*)(X + (size_t)gr * 256 + k0 + kq)
                                 : make_float4(0.f, 0.f, 0.f, 0.f);
            As[kq + 0][r] = av.x; As[kq + 1][r] = av.y;
            As[kq + 2][r] = av.z; As[kq + 3][r] = av.w;
        }
        {   // stage B tile (16 k x 128 cols)
            int idx = tid;
#pragma unroll
            for (int rep = 0; rep < 2; ++rep, idx += 256) {
                int kr = idx >> 5, cq = (idx & 31) * 4;
                *(float4*)&Bs[kr][cq] = *(const float4*)(W + (size_t)(k0 + kr) * 128 + cq);
            }
        }
        __syncthreads();
#pragma unroll
        for (int k = 0; k < 16; ++k) {
            float4 a0 = *(float4*)&As[k][ty * 8];
            float4 a1 = *(float4*)&As[k][ty * 8 + 4];
            float4 bv = *(float4*)&Bs[k][tx * 4];
            float a[8] = {a0.x, a0.y, a0.z, a0.w, a1.x, a1.y, a1.z, a1.w};
            float b[4] = {bv.x, bv.y, bv.z, bv.w};
#pragma unroll
            for (int i = 0; i < 8; ++i)
#pragma unroll
                for (int j = 0; j < 4; ++j)
                    acc[i][j] = fmaf(a[i], b[j], acc[i][j]);
        }
        __syncthreads();
    }
#pragma unroll
    for (int i = 0; i < 8; ++i) {
        int gr = brow + ty * 8 + i;
        if (gr < n) {
            float4 v = make_float4(acc[i][0], acc[i][1], acc[i][2], acc[i][3]);
            *(float4*)(H1 + (size_t)gr * 128 + tx * 4) = v;
        }
    }
}

// ---------------- node attention scores: sigmoid(sum_c h[n,h,c]*att[h,c]) -----

__global__ void score_k(const float* __restrict__ Hm, const float* __restrict__ att,
                        float* __restrict__ S, int n, int cph) {
    int t = blockIdx.x * blockDim.x + threadIdx.x;
    if (t >= n * 4) return;
    int node = t >> 2, h = t & 3;
    int cdim = cph * 4;
    const float* row = Hm + (size_t)node * cdim + h * cph;
    const float* a = att + h * cph;
    float sum = 0.f;
    for (int c = 0; c < cph; ++c) sum = fmaf(row[c], a[c], sum);
    S[t] = 1.f / (1.f + __expf(-sum));
}

// ---------------- conv1: wave per dst, 128 channels (2/lane), ELU -----------

__global__ __launch_bounds__(256) void conv1_k(const float* __restrict__ H1,
                                               const float* __restrict__ S,
                                               const int* __restrict__ rowstart,
                                               const int* __restrict__ csrc,
                                               const float* __restrict__ b1,
                                               float* __restrict__ Hout, int n) {
    int wave = (int)((blockIdx.x * blockDim.x + threadIdx.x) >> 6);
    int lane = threadIdx.x & 63;
    if (wave >= n) return;
    int dst = wave;
    int hd = lane >> 4;            // 2 channels/lane -> head = (2*lane)/32
    float si = S[dst * 4 + hd];
    int rs = rowstart[dst], re = rowstart[dst + 1];
    float m = -1e30f;
    for (int i = rs; i < re; ++i) {
        int src = csrc[i];
        float sj = S[src * 4 + hd];
        float logit = si * sj + (1.f - si) * (1.f - sj);
        m = fmaxf(m, logit);
    }
    float z = 0.f, acc0 = 0.f, acc1 = 0.f;
    for (int i = rs; i < re; ++i) {
        int src = csrc[i];
        float sj = S[src * 4 + hd];
        float logit = si * sj + (1.f - si) * (1.f - sj);
        float w = __expf(logit - m);
        z += w;
        float2 hv = *(const float2*)(H1 + (size_t)src * 128 + lane * 2);
        acc0 = fmaf(w, hv.x, acc0);
        acc1 = fmaf(w, hv.y, acc1);
    }
    float inv = 1.f / (z + 1e-16f);
    float r0 = acc0 * inv + b1[lane * 2];
    float r1 = acc1 * inv + b1[lane * 2 + 1];
    r0 = (r0 > 0.f) ? r0 : (__expf(r0) - 1.f);   // ELU
    r1 = (r1 > 0.f) ? r1 : (__expf(r1) - 1.f);
    *(float2*)(Hout + (size_t)dst * 128 + lane * 2) = make_float2(r0, r1);
}

// ---------------- GEMM2: [N,128] @ [128,32] ----------------

__global__ __launch_bounds__(256) void gemm2_k(const float* __restrict__ Hin,
                                               const float* __restrict__ W2,
                                               float* __restrict__ H2, int n) {
    __shared__ float rows[8][128];
    int tid = threadIdx.x;
    int node0 = blockIdx.x * 8;
    {
        int r = tid >> 5, q = (tid & 31) * 4;
        int gn = node0 + r;
        float4 v = (gn < n) ? *(const float4*)(Hin + (size_t)gn * 128 + q)
                            : make_float4(0.f, 0.f, 0.f, 0.f);
        *(float4*)&rows[r][q] = v;
    }
    __syncthreads();
    int r = tid >> 5;   // 0..7
    int c = tid & 31;   // 0..31
    int gn = node0 + r;
    if (gn >= n) return;
    float sum = 0.f;
#pragma unroll 4
    for (int k = 0; k < 128; ++k) sum = fmaf(rows[r][k], W2[k * 32 + c], sum);
    H2[(size_t)gn * 32 + c] = sum;
}

// ---------------- conv2: wave handles 2 dsts (32 lanes each), head-mean -----

__global__ __launch_bounds__(256) void conv2_k(const float* __restrict__ H2,
                                               const float* __restrict__ S,
                                               const int* __restrict__ rowstart,
                                               const int* __restrict__ csrc,
                                               const float* __restrict__ b2,
                                               float* __restrict__ Out, int n) {
    int wave = (int)((blockIdx.x * blockDim.x + threadIdx.x) >> 6);
    int lane = threadIdx.x & 63;
    int half = lane >> 5;
    int c = lane & 31;             // channel = head*8 + o
    int dst = wave * 2 + half;
    if (dst >= n) return;
    int hd = c >> 3;
    float si = S[dst * 4 + hd];
    int rs = rowstart[dst], re = rowstart[dst + 1];
    float m = -1e30f;
    for (int i = rs; i < re; ++i) {
        int src = csrc[i];
        float sj = S[src * 4 + hd];
        float logit = si * sj + (1.f - si) * (1.f - sj);
        m = fmaxf(m, logit);
    }
    float z = 0.f, acc = 0.f;
    for (int i = rs; i < re; ++i) {
        int src = csrc[i];
        float sj = S[src * 4 + hd];
        float logit = si * sj + (1.f - si) * (1.f - sj);
        float w = __expf(logit - m);
        z += w;
        acc = fmaf(w, H2[(size_t)src * 32 + c], acc);
    }
    float r = acc / (z + 1e-16f);
    // mean over heads: channels h*8+o, sum over h via xor-8 and xor-16 within 32
    r += __shfl_xor(r, 8, 32);
    r += __shfl_xor(r, 16, 32);
    if (hd == 0) Out[(size_t)dst * 8 + c] = r * 0.25f + b2[c];
}

// ---------------- launcher ----------------

extern "C" void kernel_launch(void* const* d_in, const int* in_sizes, int n_in,
                              void* d_out, int out_size, void* d_ws, size_t ws_size,
                              hipStream_t stream) {
    const float* x    = (const float*)d_in[0];
    const int*   edge = (const int*)d_in[1];
    const float* W1   = (const float*)d_in[2];
    const float* att1 = (const float*)d_in[3];
    const float* b1   = (const float*)d_in[4];
    const float* W2   = (const float*)d_in[5];
    const float* att2 = (const float*)d_in[6];
    const float* b2   = (const float*)d_in[7];

    int N  = in_sizes[0] / 256;
    int E  = in_sizes[1] / 2;
    int ET = E + N;
    const int* srcA = edge;
    const int* dstA = edge + E;

    // workspace layout (~56 MB)
    char* ws = (char*)d_ws;
    float* h1   = (float*)ws;  ws += (size_t)N * 128 * sizeof(float);
    float* helu = (float*)ws;  ws += (size_t)N * 128 * sizeof(float);
    float* s    = (float*)ws;  ws += (size_t)N * 4 * sizeof(float);
    int* rowstart = (int*)ws;  ws += (size_t)(N + 1) * sizeof(int);
    int* deg      = (int*)ws;  ws += (size_t)N * sizeof(int);
    int* cursor   = (int*)ws;  ws += (size_t)N * sizeof(int);
    int* csrc     = (int*)ws;  ws += (size_t)ET * sizeof(int);
    float* h2 = h1;  // reuse h1 region after conv1 consumed it

    hipMemsetAsync(deg, 0, (size_t)N * sizeof(int), stream);
    hipMemsetAsync(cursor, 0, (size_t)N * sizeof(int), stream);

    int eb = (ET + 255) / 256;
    count_deg_k<<<eb, 256, 0, stream>>>(dstA, E, ET, deg);
    scan_k<<<1, 1024, 0, stream>>>(deg, rowstart, N);
    scatter_k<<<eb, 256, 0, stream>>>(srcA, dstA, E, ET, rowstart, cursor, csrc);

    gemm1_k<<<(N + 63) / 64, 256, 0, stream>>>(x, W1, h1, N);
    score_k<<<(N * 4 + 255) / 256, 256, 0, stream>>>(h1, att1, s, N, 32);
    conv1_k<<<(N + 3) / 4, 256, 0, stream>>>(h1, s, rowstart, csrc, b1, helu, N);

    gemm2_k<<<(N + 7) / 8, 256, 0, stream>>>(helu, W2, h2, N);
    score_k<<<(N * 4 + 255) / 256, 256, 0, stream>>>(h2, att2, s, N, 8);
    int waves2 = (N + 1) / 2;
    conv2_k<<<(waves2 * 64 + 255) / 256, 256, 0, stream>>>(h2, s, rowstart, csrc, b2,
                                                           (float*)d_out, N);
}

// Round 2
// 394.199 us; speedup vs baseline: 1.3113x; 1.3113x over previous
//
#include <hip/hip_runtime.h>
#include <math.h>

// Problem constants (from reference): N=50000, E=800000, IN_DIM=256,
// H=4 heads, HID=32 (conv1 per-head), OUT=8 (conv2 per-head).
// HDIM1 = H*HID = 128, HDIM2 = H*OUT = 32.
//
// NOTE: softmax logit = si*sj + (1-si)(1-sj) with si,sj in (0,1) is bounded
// in (0,1), so exp(logit) cannot overflow -> the segment-max subtraction is
// mathematically a no-op for the softmax ratio and is omitted (single pass).

// ---------------- CSR build ----------------

__global__ void count_deg_k(const int* __restrict__ dstA, int E, int ET,
                            int* __restrict__ deg) {
    int e = blockIdx.x * blockDim.x + threadIdx.x;
    if (e >= ET) return;
    int d = (e < E) ? dstA[e] : (e - E);   // self-loop edges appended
    atomicAdd(&deg[d], 1);
}

__global__ void scan_k(const int* __restrict__ deg, int* __restrict__ rowstart,
                       int n) {
    __shared__ int buf[1024];
    __shared__ int carry;
    if (threadIdx.x == 0) carry = 0;
    __syncthreads();
    for (int base = 0; base < n; base += 1024) {
        int i = base + (int)threadIdx.x;
        int v = (i < n) ? deg[i] : 0;
        buf[threadIdx.x] = v;
        __syncthreads();
        for (int off = 1; off < 1024; off <<= 1) {
            int t = (threadIdx.x >= (unsigned)off) ? buf[threadIdx.x - off] : 0;
            __syncthreads();
            buf[threadIdx.x] += t;
            __syncthreads();
        }
        if (i < n) rowstart[i] = carry + buf[threadIdx.x] - v;  // exclusive
        __syncthreads();
        if (threadIdx.x == 0) carry += buf[1023];
        __syncthreads();
    }
    if (threadIdx.x == 0) rowstart[n] = carry;
}

__global__ void scatter_k(const int* __restrict__ srcA, const int* __restrict__ dstA,
                          int E, int ET, const int* __restrict__ rowstart,
                          int* __restrict__ cursor, int* __restrict__ csrc) {
    int e = blockIdx.x * blockDim.x + threadIdx.x;
    if (e >= ET) return;
    int d, s;
    if (e < E) { d = dstA[e]; s = srcA[e]; } else { d = e - E; s = e - E; }
    int pos = atomicAdd(&cursor[d], 1);
    csrc[rowstart[d] + pos] = s;   // store SRC node id directly
}

// ---------------- GEMM1: [N,256] @ [256,128] ----------------

__global__ __launch_bounds__(256) void gemm1_k(const float* __restrict__ X,
                                               const float* __restrict__ W,
                                               float* __restrict__ H1, int n) {
    __shared__ float As[16][64];    // transposed: [k][m]
    __shared__ float Bs[16][128];   // [k][n]
    int tid = threadIdx.x;
    int tx = tid & 31;     // 32 col-groups of 4
    int ty = tid >> 5;     // 8 row-groups of 8
    int brow = blockIdx.x * 64;
    float acc[8][4];
#pragma unroll
    for (int i = 0; i < 8; ++i)
#pragma unroll
        for (int j = 0; j < 4; ++j) acc[i][j] = 0.f;

    for (int k0 = 0; k0 < 256; k0 += 16) {
        {   // stage A tile (64 rows x 16 k), transposed into LDS
            int r = tid >> 2, kq = (tid & 3) * 4;
            int gr = brow + r;
            float4 av = (gr < n) ? *(const float4*)(X + (size_t)gr * 256 + k0 + kq)
                                 : make_float4(0.f, 0.f, 0.f, 0.f);
            As[kq + 0][r] = av.x; As[kq + 1][r] = av.y;
            As[kq + 2][r] = av.z; As[kq + 3][r] = av.w;
        }
        {   // stage B tile (16 k x 128 cols)
            int idx = tid;
#pragma unroll
            for (int rep = 0; rep < 2; ++rep, idx += 256) {
                int kr = idx >> 5, cq = (idx & 31) * 4;
                *(float4*)&Bs[kr][cq] = *(const float4*)(W + (size_t)(k0 + kr) * 128 + cq);
            }
        }
        __syncthreads();
#pragma unroll
        for (int k = 0; k < 16; ++k) {
            float4 a0 = *(float4*)&As[k][ty * 8];
            float4 a1 = *(float4*)&As[k][ty * 8 + 4];
            float4 bv = *(float4*)&Bs[k][tx * 4];
            float a[8] = {a0.x, a0.y, a0.z, a0.w, a1.x, a1.y, a1.z, a1.w};
            float b[4] = {bv.x, bv.y, bv.z, bv.w};
#pragma unroll
            for (int i = 0; i < 8; ++i)
#pragma unroll
                for (int j = 0; j < 4; ++j)
                    acc[i][j] = fmaf(a[i], b[j], acc[i][j]);
        }
        __syncthreads();
    }
#pragma unroll
    for (int i = 0; i < 8; ++i) {
        int gr = brow + ty * 8 + i;
        if (gr < n) {
            float4 v = make_float4(acc[i][0], acc[i][1], acc[i][2], acc[i][3]);
            *(float4*)(H1 + (size_t)gr * 128 + tx * 4) = v;
        }
    }
}

// ---------------- node attention scores: sigmoid(sum_c h[n,h,c]*att[h,c]) -----

__global__ void score_k(const float* __restrict__ Hm, const float* __restrict__ att,
                        float* __restrict__ S, int n, int cph) {
    int t = blockIdx.x * blockDim.x + threadIdx.x;
    if (t >= n * 4) return;
    int node = t >> 2, h = t & 3;
    int cdim = cph * 4;
    const float* row = Hm + (size_t)node * cdim + h * cph;
    const float* a = att + h * cph;
    float sum = 0.f;
    for (int c = 0; c < cph; c += 4) {
        float4 rv = *(const float4*)(row + c);
        float4 av = *(const float4*)(a + c);
        sum = fmaf(rv.x, av.x, sum);
        sum = fmaf(rv.y, av.y, sum);
        sum = fmaf(rv.z, av.z, sum);
        sum = fmaf(rv.w, av.w, sum);
    }
    S[t] = 1.f / (1.f + __expf(-sum));
}

// ---------------- conv1: wave per dst, 128 channels (2/lane), ELU -----------
// single pass (no segment max needed -- logits bounded), unrolled by 2

__global__ __launch_bounds__(256) void conv1_k(const float* __restrict__ H1,
                                               const float* __restrict__ S,
                                               const int* __restrict__ rowstart,
                                               const int* __restrict__ csrc,
                                               const float* __restrict__ b1,
                                               float* __restrict__ Hout, int n) {
    int wave = (int)((blockIdx.x * blockDim.x + threadIdx.x) >> 6);
    int lane = threadIdx.x & 63;
    if (wave >= n) return;
    int dst = wave;
    int hd = lane >> 4;            // 2 channels/lane -> head = (2*lane)/32
    float si = S[dst * 4 + hd];
    float omsi = 1.f - si;
    int rs = rowstart[dst], re = rowstart[dst + 1];

    float zA = 0.f, a0A = 0.f, a1A = 0.f;
    float zB = 0.f, a0B = 0.f, a1B = 0.f;
    int i = rs;
    for (; i + 1 < re; i += 2) {
        int s0 = csrc[i], s1 = csrc[i + 1];
        float sj0 = S[s0 * 4 + hd];
        float sj1 = S[s1 * 4 + hd];
        const float2 h0 = *(const float2*)(H1 + (size_t)s0 * 128 + lane * 2);
        const float2 h1 = *(const float2*)(H1 + (size_t)s1 * 128 + lane * 2);
        float w0 = __expf(fmaf(si, sj0, omsi * (1.f - sj0)));
        float w1 = __expf(fmaf(si, sj1, omsi * (1.f - sj1)));
        zA += w0;             zB += w1;
        a0A = fmaf(w0, h0.x, a0A);  a0B = fmaf(w1, h1.x, a0B);
        a1A = fmaf(w0, h0.y, a1A);  a1B = fmaf(w1, h1.y, a1B);
    }
    if (i < re) {
        int s0 = csrc[i];
        float sj0 = S[s0 * 4 + hd];
        const float2 h0 = *(const float2*)(H1 + (size_t)s0 * 128 + lane * 2);
        float w0 = __expf(fmaf(si, sj0, omsi * (1.f - sj0)));
        zA += w0;
        a0A = fmaf(w0, h0.x, a0A);
        a1A = fmaf(w0, h0.y, a1A);
    }
    float z = zA + zB;
    float inv = 1.f / (z + 1e-16f);
    float r0 = (a0A + a0B) * inv + b1[lane * 2];
    float r1 = (a1A + a1B) * inv + b1[lane * 2 + 1];
    r0 = (r0 > 0.f) ? r0 : (__expf(r0) - 1.f);   // ELU
    r1 = (r1 > 0.f) ? r1 : (__expf(r1) - 1.f);
    *(float2*)(Hout + (size_t)dst * 128 + lane * 2) = make_float2(r0, r1);
}

// ---------------- GEMM2: [N,128] @ [128,32] ----------------

__global__ __launch_bounds__(256) void gemm2_k(const float* __restrict__ Hin,
                                               const float* __restrict__ W2,
                                               float* __restrict__ H2, int n) {
    __shared__ float rows[8][128];
    int tid = threadIdx.x;
    int node0 = blockIdx.x * 8;
    {
        int r = tid >> 5, q = (tid & 31) * 4;
        int gn = node0 + r;
        float4 v = (gn < n) ? *(const float4*)(Hin + (size_t)gn * 128 + q)
                            : make_float4(0.f, 0.f, 0.f, 0.f);
        *(float4*)&rows[r][q] = v;
    }
    __syncthreads();
    int r = tid >> 5;   // 0..7
    int c = tid & 31;   // 0..31
    int gn = node0 + r;
    if (gn >= n) return;
    float sum = 0.f;
#pragma unroll 4
    for (int k = 0; k < 128; ++k) sum = fmaf(rows[r][k], W2[k * 32 + c], sum);
    H2[(size_t)gn * 32 + c] = sum;
}

// ---------------- conv2: wave handles 2 dsts (32 lanes each), head-mean -----
// single pass (no segment max), unrolled by 2

__global__ __launch_bounds__(256) void conv2_k(const float* __restrict__ H2,
                                               const float* __restrict__ S,
                                               const int* __restrict__ rowstart,
                                               const int* __restrict__ csrc,
                                               const float* __restrict__ b2,
                                               float* __restrict__ Out, int n) {
    int wave = (int)((blockIdx.x * blockDim.x + threadIdx.x) >> 6);
    int lane = threadIdx.x & 63;
    int half = lane >> 5;
    int c = lane & 31;             // channel = head*8 + o
    int dst = wave * 2 + half;
    if (dst >= n) return;
    int hd = c >> 3;
    float si = S[dst * 4 + hd];
    float omsi = 1.f - si;
    int rs = rowstart[dst], re = rowstart[dst + 1];

    float zA = 0.f, accA = 0.f;
    float zB = 0.f, accB = 0.f;
    int i = rs;
    for (; i + 1 < re; i += 2) {
        int s0 = csrc[i], s1 = csrc[i + 1];
        float sj0 = S[s0 * 4 + hd];
        float sj1 = S[s1 * 4 + hd];
        float v0 = H2[(size_t)s0 * 32 + c];
        float v1 = H2[(size_t)s1 * 32 + c];
        float w0 = __expf(fmaf(si, sj0, omsi * (1.f - sj0)));
        float w1 = __expf(fmaf(si, sj1, omsi * (1.f - sj1)));
        zA += w0;  accA = fmaf(w0, v0, accA);
        zB += w1;  accB = fmaf(w1, v1, accB);
    }
    if (i < re) {
        int s0 = csrc[i];
        float sj0 = S[s0 * 4 + hd];
        float v0 = H2[(size_t)s0 * 32 + c];
        float w0 = __expf(fmaf(si, sj0, omsi * (1.f - sj0)));
        zA += w0;  accA = fmaf(w0, v0, accA);
    }
    float r = (accA + accB) / ((zA + zB) + 1e-16f);
    // mean over heads: channels h*8+o, sum over h via xor-8 and xor-16 within 32
    r += __shfl_xor(r, 8, 32);
    r += __shfl_xor(r, 16, 32);
    if (hd == 0) Out[(size_t)dst * 8 + c] = r * 0.25f + b2[c];
}

// ---------------- launcher ----------------

extern "C" void kernel_launch(void* const* d_in, const int* in_sizes, int n_in,
                              void* d_out, int out_size, void* d_ws, size_t ws_size,
                              hipStream_t stream) {
    const float* x    = (const float*)d_in[0];
    const int*   edge = (const int*)d_in[1];
    const float* W1   = (const float*)d_in[2];
    const float* att1 = (const float*)d_in[3];
    const float* b1   = (const float*)d_in[4];
    const float* W2   = (const float*)d_in[5];
    const float* att2 = (const float*)d_in[6];
    const float* b2   = (const float*)d_in[7];

    int N  = in_sizes[0] / 256;
    int E  = in_sizes[1] / 2;
    int ET = E + N;
    const int* srcA = edge;
    const int* dstA = edge + E;

    // workspace layout (~56 MB)
    char* ws = (char*)d_ws;
    float* h1   = (float*)ws;  ws += (size_t)N * 128 * sizeof(float);
    float* helu = (float*)ws;  ws += (size_t)N * 128 * sizeof(float);
    float* s    = (float*)ws;  ws += (size_t)N * 4 * sizeof(float);
    int* rowstart = (int*)ws;  ws += (size_t)(N + 1) * sizeof(int);
    int* deg      = (int*)ws;  ws += (size_t)N * sizeof(int);
    int* cursor   = (int*)ws;  ws += (size_t)N * sizeof(int);
    int* csrc     = (int*)ws;  ws += (size_t)ET * sizeof(int);
    float* h2 = h1;  // reuse h1 region after conv1 consumed it

    hipMemsetAsync(deg, 0, (size_t)N * sizeof(int), stream);
    hipMemsetAsync(cursor, 0, (size_t)N * sizeof(int), stream);

    int eb = (ET + 255) / 256;
    count_deg_k<<<eb, 256, 0, stream>>>(dstA, E, ET, deg);
    scan_k<<<1, 1024, 0, stream>>>(deg, rowstart, N);
    scatter_k<<<eb, 256, 0, stream>>>(srcA, dstA, E, ET, rowstart, cursor, csrc);

    gemm1_k<<<(N + 63) / 64, 256, 0, stream>>>(x, W1, h1, N);
    score_k<<<(N * 4 + 255) / 256, 256, 0, stream>>>(h1, att1, s, N, 32);
    conv1_k<<<(N + 3) / 4, 256, 0, stream>>>(h1, s, rowstart, csrc, b1, helu, N);

    gemm2_k<<<(N + 7) / 8, 256, 0, stream>>>(helu, W2, h2, N);
    score_k<<<(N * 4 + 255) / 256, 256, 0, stream>>>(h2, att2, s, N, 8);
    int waves2 = (N + 1) / 2;
    conv2_k<<<(waves2 * 64 + 255) / 256, 256, 0, stream>>>(h2, s, rowstart, csrc, b2,
                                                           (float*)d_out, N);
}

// Round 3
// 291.548 us; speedup vs baseline: 1.7730x; 1.3521x over previous
//
#include <hip/hip_runtime.h>
#include <math.h>

// Problem constants (from reference): N=50000, E=800000, IN_DIM=256,
// H=4 heads, HID=32 (conv1 per-head), OUT=8 (conv2 per-head).
// HDIM1 = H*HID = 128, HDIM2 = H*OUT = 32.
//
// NOTE: softmax logit = si*sj + (1-si)(1-sj) with si,sj in (0,1) is bounded
// in (0,1), so exp(logit) cannot overflow -> the segment-max subtraction is
// mathematically a no-op for the softmax ratio and is omitted (single pass).

// ---------------- CSR build ----------------

__global__ void count_deg_k(const int* __restrict__ dstA, int E, int ET,
                            int* __restrict__ deg) {
    int e = blockIdx.x * blockDim.x + threadIdx.x;
    if (e >= ET) return;
    int d = (e < E) ? dstA[e] : (e - E);   // self-loop edges appended
    atomicAdd(&deg[d], 1);
}

// multi-block exclusive scan: A) per-1024-chunk scan, B) scan chunk sums,
// C) add chunk offsets.

__global__ __launch_bounds__(256) void scan_a_k(const int* __restrict__ deg, int n,
                                                int* __restrict__ rowstart,
                                                int* __restrict__ bsum) {
    __shared__ int ts[256];
    int t = threadIdx.x;
    int idx = blockIdx.x * 1024 + t * 4;
    int4 v = make_int4(0, 0, 0, 0);
    if (idx + 3 < n) {
        v = *(const int4*)(deg + idx);
    } else {
        if (idx < n)     v.x = deg[idx];
        if (idx + 1 < n) v.y = deg[idx + 1];
        if (idx + 2 < n) v.z = deg[idx + 2];
        if (idx + 3 < n) v.w = deg[idx + 3];
    }
    int s = v.x + v.y + v.z + v.w;
    ts[t] = s;
    __syncthreads();
#pragma unroll
    for (int off = 1; off < 256; off <<= 1) {
        int u = (t >= off) ? ts[t - off] : 0;
        __syncthreads();
        ts[t] += u;
        __syncthreads();
    }
    int excl = ts[t] - s;
    int p1 = excl + v.x, p2 = p1 + v.y, p3 = p2 + v.z;
    if (idx < n)     rowstart[idx]     = excl;
    if (idx + 1 < n) rowstart[idx + 1] = p1;
    if (idx + 2 < n) rowstart[idx + 2] = p2;
    if (idx + 3 < n) rowstart[idx + 3] = p3;
    if (t == 255) bsum[blockIdx.x] = ts[255];
}

__global__ __launch_bounds__(256) void scan_b_k(const int* __restrict__ bsum, int nb,
                                                int* __restrict__ boff,
                                                int* __restrict__ totalp) {
    __shared__ int ts[256];
    int t = threadIdx.x;
    int v = (t < nb) ? bsum[t] : 0;
    ts[t] = v;
    __syncthreads();
#pragma unroll
    for (int off = 1; off < 256; off <<= 1) {
        int u = (t >= off) ? ts[t - off] : 0;
        __syncthreads();
        ts[t] += u;
        __syncthreads();
    }
    if (t < nb) boff[t] = ts[t] - v;
    if (t == nb - 1) *totalp = ts[t];   // rowstart[N] = total edge count
}

__global__ void scan_c_k(int* __restrict__ rowstart, const int* __restrict__ boff,
                         int n) {
    int i = blockIdx.x * blockDim.x + threadIdx.x;
    if (i < n) rowstart[i] += boff[i >> 10];
}

__global__ void scatter_k(const int* __restrict__ srcA, const int* __restrict__ dstA,
                          int E, int ET, const int* __restrict__ rowstart,
                          int* __restrict__ cursor, int* __restrict__ csrc) {
    int e = blockIdx.x * blockDim.x + threadIdx.x;
    if (e >= ET) return;
    int d, s;
    if (e < E) { d = dstA[e]; s = srcA[e]; } else { d = e - E; s = e - E; }
    int pos = atomicAdd(&cursor[d], 1);
    csrc[rowstart[d] + pos] = s;   // store SRC node id directly
}

// ---------------- GEMM1: [N,256] @ [256,128], 128x128 tile, 8x8 micro ------

__global__ __launch_bounds__(256) void gemm1_k(const float* __restrict__ X,
                                               const float* __restrict__ W,
                                               float* __restrict__ H1, int n) {
    __shared__ float As[16][128];   // transposed: [k][m]
    __shared__ float Bs[16][128];   // [k][n]
    int tid = threadIdx.x;
    int tx = tid & 15;     // 16 col-groups of 8
    int ty = tid >> 4;     // 16 row-groups of 8
    int brow = blockIdx.x * 128;
    float acc[8][8];
#pragma unroll
    for (int i = 0; i < 8; ++i)
#pragma unroll
        for (int j = 0; j < 8; ++j) acc[i][j] = 0.f;

    for (int k0 = 0; k0 < 256; k0 += 16) {
        {   // stage A tile (128 rows x 16 k), transposed into LDS
            int r = tid >> 1, kq = (tid & 1) * 8;
            int gr = brow + r;
            float4 av0, av1;
            if (gr < n) {
                av0 = *(const float4*)(X + (size_t)gr * 256 + k0 + kq);
                av1 = *(const float4*)(X + (size_t)gr * 256 + k0 + kq + 4);
            } else {
                av0 = av1 = make_float4(0.f, 0.f, 0.f, 0.f);
            }
            As[kq + 0][r] = av0.x; As[kq + 1][r] = av0.y;
            As[kq + 2][r] = av0.z; As[kq + 3][r] = av0.w;
            As[kq + 4][r] = av1.x; As[kq + 5][r] = av1.y;
            As[kq + 6][r] = av1.z; As[kq + 7][r] = av1.w;
        }
        {   // stage B tile (16 k x 128 cols)
            int idx = tid;
#pragma unroll
            for (int rep = 0; rep < 2; ++rep, idx += 256) {
                int kr = idx >> 5, cq = (idx & 31) * 4;
                *(float4*)&Bs[kr][cq] = *(const float4*)(W + (size_t)(k0 + kr) * 128 + cq);
            }
        }
        __syncthreads();
#pragma unroll
        for (int k = 0; k < 16; ++k) {
            float4 a0 = *(float4*)&As[k][ty * 8];
            float4 a1 = *(float4*)&As[k][ty * 8 + 4];
            float4 b0 = *(float4*)&Bs[k][tx * 8];
            float4 b1 = *(float4*)&Bs[k][tx * 8 + 4];
            float a[8] = {a0.x, a0.y, a0.z, a0.w, a1.x, a1.y, a1.z, a1.w};
            float b[8] = {b0.x, b0.y, b0.z, b0.w, b1.x, b1.y, b1.z, b1.w};
#pragma unroll
            for (int i = 0; i < 8; ++i)
#pragma unroll
                for (int j = 0; j < 8; ++j)
                    acc[i][j] = fmaf(a[i], b[j], acc[i][j]);
        }
        __syncthreads();
    }
#pragma unroll
    for (int i = 0; i < 8; ++i) {
        int gr = brow + ty * 8 + i;
        if (gr < n) {
            *(float4*)(H1 + (size_t)gr * 128 + tx * 8) =
                make_float4(acc[i][0], acc[i][1], acc[i][2], acc[i][3]);
            *(float4*)(H1 + (size_t)gr * 128 + tx * 8 + 4) =
                make_float4(acc[i][4], acc[i][5], acc[i][6], acc[i][7]);
        }
    }
}

// ---------------- node attention scores: sigmoid(sum_c h[n,h,c]*att[h,c]) -----

__global__ void score_k(const float* __restrict__ Hm, const float* __restrict__ att,
                        float* __restrict__ S, int n, int cph) {
    int t = blockIdx.x * blockDim.x + threadIdx.x;
    if (t >= n * 4) return;
    int node = t >> 2, h = t & 3;
    int cdim = cph * 4;
    const float* row = Hm + (size_t)node * cdim + h * cph;
    const float* a = att + h * cph;
    float sum = 0.f;
    for (int c = 0; c < cph; c += 4) {
        float4 rv = *(const float4*)(row + c);
        float4 av = *(const float4*)(a + c);
        sum = fmaf(rv.x, av.x, sum);
        sum = fmaf(rv.y, av.y, sum);
        sum = fmaf(rv.z, av.z, sum);
        sum = fmaf(rv.w, av.w, sum);
    }
    S[t] = 1.f / (1.f + __expf(-sum));
}

// ---------------- conv1: wave per dst, 128 channels (2/lane), ELU -----------
// single pass, unrolled by 4 (4 independent gather chains)

__global__ __launch_bounds__(256) void conv1_k(const float* __restrict__ H1,
                                               const float* __restrict__ S,
                                               const int* __restrict__ rowstart,
                                               const int* __restrict__ csrc,
                                               const float* __restrict__ b1,
                                               float* __restrict__ Hout, int n) {
    int wave = (int)((blockIdx.x * blockDim.x + threadIdx.x) >> 6);
    int lane = threadIdx.x & 63;
    if (wave >= n) return;
    int dst = wave;
    int hd = lane >> 4;            // 2 channels/lane -> head = (2*lane)/32
    float si = S[dst * 4 + hd];
    float omsi = 1.f - si;
    int rs = rowstart[dst], re = rowstart[dst + 1];

    float z0 = 0.f, z1 = 0.f, z2 = 0.f, z3 = 0.f;
    float x0 = 0.f, x1 = 0.f, x2 = 0.f, x3 = 0.f;
    float y0 = 0.f, y1 = 0.f, y2 = 0.f, y3 = 0.f;
    int i = rs;
    for (; i + 3 < re; i += 4) {
        int s0 = csrc[i], s1 = csrc[i + 1], s2 = csrc[i + 2], s3 = csrc[i + 3];
        float sj0 = S[s0 * 4 + hd], sj1 = S[s1 * 4 + hd];
        float sj2 = S[s2 * 4 + hd], sj3 = S[s3 * 4 + hd];
        float2 h0 = *(const float2*)(H1 + (size_t)s0 * 128 + lane * 2);
        float2 h1 = *(const float2*)(H1 + (size_t)s1 * 128 + lane * 2);
        float2 h2 = *(const float2*)(H1 + (size_t)s2 * 128 + lane * 2);
        float2 h3 = *(const float2*)(H1 + (size_t)s3 * 128 + lane * 2);
        float w0 = __expf(fmaf(si, sj0, omsi * (1.f - sj0)));
        float w1 = __expf(fmaf(si, sj1, omsi * (1.f - sj1)));
        float w2 = __expf(fmaf(si, sj2, omsi * (1.f - sj2)));
        float w3 = __expf(fmaf(si, sj3, omsi * (1.f - sj3)));
        z0 += w0; z1 += w1; z2 += w2; z3 += w3;
        x0 = fmaf(w0, h0.x, x0); x1 = fmaf(w1, h1.x, x1);
        x2 = fmaf(w2, h2.x, x2); x3 = fmaf(w3, h3.x, x3);
        y0 = fmaf(w0, h0.y, y0); y1 = fmaf(w1, h1.y, y1);
        y2 = fmaf(w2, h2.y, y2); y3 = fmaf(w3, h3.y, y3);
    }
    for (; i < re; ++i) {
        int s0 = csrc[i];
        float sj0 = S[s0 * 4 + hd];
        float2 h0 = *(const float2*)(H1 + (size_t)s0 * 128 + lane * 2);
        float w0 = __expf(fmaf(si, sj0, omsi * (1.f - sj0)));
        z0 += w0;
        x0 = fmaf(w0, h0.x, x0);
        y0 = fmaf(w0, h0.y, y0);
    }
    float inv = 1.f / ((z0 + z1) + (z2 + z3) + 1e-16f);
    float r0 = ((x0 + x1) + (x2 + x3)) * inv + b1[lane * 2];
    float r1 = ((y0 + y1) + (y2 + y3)) * inv + b1[lane * 2 + 1];
    r0 = (r0 > 0.f) ? r0 : (__expf(r0) - 1.f);   // ELU
    r1 = (r1 > 0.f) ? r1 : (__expf(r1) - 1.f);
    *(float2*)(Hout + (size_t)dst * 128 + lane * 2) = make_float2(r0, r1);
}

// ---------------- GEMM2: [N,128] @ [128,32] ----------------

__global__ __launch_bounds__(256) void gemm2_k(const float* __restrict__ Hin,
                                               const float* __restrict__ W2,
                                               float* __restrict__ H2, int n) {
    __shared__ float rows[8][128];
    int tid = threadIdx.x;
    int node0 = blockIdx.x * 8;
    {
        int r = tid >> 5, q = (tid & 31) * 4;
        int gn = node0 + r;
        float4 v = (gn < n) ? *(const float4*)(Hin + (size_t)gn * 128 + q)
                            : make_float4(0.f, 0.f, 0.f, 0.f);
        *(float4*)&rows[r][q] = v;
    }
    __syncthreads();
    int r = tid >> 5;   // 0..7
    int c = tid & 31;   // 0..31
    int gn = node0 + r;
    if (gn >= n) return;
    float sum = 0.f;
#pragma unroll 4
    for (int k = 0; k < 128; ++k) sum = fmaf(rows[r][k], W2[k * 32 + c], sum);
    H2[(size_t)gn * 32 + c] = sum;
}

// ---------------- conv2: wave handles 2 dsts (32 lanes each), head-mean -----
// single pass, unrolled by 4

__global__ __launch_bounds__(256) void conv2_k(const float* __restrict__ H2,
                                               const float* __restrict__ S,
                                               const int* __restrict__ rowstart,
                                               const int* __restrict__ csrc,
                                               const float* __restrict__ b2,
                                               float* __restrict__ Out, int n) {
    int wave = (int)((blockIdx.x * blockDim.x + threadIdx.x) >> 6);
    int lane = threadIdx.x & 63;
    int half = lane >> 5;
    int c = lane & 31;             // channel = head*8 + o
    int dst = wave * 2 + half;
    if (dst >= n) return;
    int hd = c >> 3;
    float si = S[dst * 4 + hd];
    float omsi = 1.f - si;
    int rs = rowstart[dst], re = rowstart[dst + 1];

    float z0 = 0.f, z1 = 0.f, z2 = 0.f, z3 = 0.f;
    float a0 = 0.f, a1 = 0.f, a2 = 0.f, a3 = 0.f;
    int i = rs;
    for (; i + 3 < re; i += 4) {
        int s0 = csrc[i], s1 = csrc[i + 1], s2 = csrc[i + 2], s3 = csrc[i + 3];
        float sj0 = S[s0 * 4 + hd], sj1 = S[s1 * 4 + hd];
        float sj2 = S[s2 * 4 + hd], sj3 = S[s3 * 4 + hd];
        float v0 = H2[(size_t)s0 * 32 + c];
        float v1 = H2[(size_t)s1 * 32 + c];
        float v2 = H2[(size_t)s2 * 32 + c];
        float v3 = H2[(size_t)s3 * 32 + c];
        float w0 = __expf(fmaf(si, sj0, omsi * (1.f - sj0)));
        float w1 = __expf(fmaf(si, sj1, omsi * (1.f - sj1)));
        float w2 = __expf(fmaf(si, sj2, omsi * (1.f - sj2)));
        float w3 = __expf(fmaf(si, sj3, omsi * (1.f - sj3)));
        z0 += w0; a0 = fmaf(w0, v0, a0);
        z1 += w1; a1 = fmaf(w1, v1, a1);
        z2 += w2; a2 = fmaf(w2, v2, a2);
        z3 += w3; a3 = fmaf(w3, v3, a3);
    }
    for (; i < re; ++i) {
        int s0 = csrc[i];
        float sj0 = S[s0 * 4 + hd];
        float v0 = H2[(size_t)s0 * 32 + c];
        float w0 = __expf(fmaf(si, sj0, omsi * (1.f - sj0)));
        z0 += w0; a0 = fmaf(w0, v0, a0);
    }
    float r = ((a0 + a1) + (a2 + a3)) / (((z0 + z1) + (z2 + z3)) + 1e-16f);
    // mean over heads: channels h*8+o, sum over h via xor-8 and xor-16 within 32
    r += __shfl_xor(r, 8, 32);
    r += __shfl_xor(r, 16, 32);
    if (hd == 0) Out[(size_t)dst * 8 + c] = r * 0.25f + b2[c];
}

// ---------------- launcher ----------------

static inline size_t align16(size_t x) { return (x + 15) & ~(size_t)15; }

extern "C" void kernel_launch(void* const* d_in, const int* in_sizes, int n_in,
                              void* d_out, int out_size, void* d_ws, size_t ws_size,
                              hipStream_t stream) {
    const float* x    = (const float*)d_in[0];
    const int*   edge = (const int*)d_in[1];
    const float* W1   = (const float*)d_in[2];
    const float* att1 = (const float*)d_in[3];
    const float* b1   = (const float*)d_in[4];
    const float* W2   = (const float*)d_in[5];
    const float* att2 = (const float*)d_in[6];
    const float* b2   = (const float*)d_in[7];

    int N  = in_sizes[0] / 256;
    int E  = in_sizes[1] / 2;
    int ET = E + N;
    int NB = (N + 1023) / 1024;     // scan chunks
    const int* srcA = edge;
    const int* dstA = edge + E;

    // workspace layout (~56 MB), all carve-outs 16B-aligned
    char* ws = (char*)d_ws;
    float* h1   = (float*)ws;  ws += align16((size_t)N * 128 * sizeof(float));
    float* helu = (float*)ws;  ws += align16((size_t)N * 128 * sizeof(float));
    float* s    = (float*)ws;  ws += align16((size_t)N * 4 * sizeof(float));
    int* rowstart = (int*)ws;  ws += align16((size_t)(N + 1) * sizeof(int));
    int* deg      = (int*)ws;  ws += align16((size_t)N * sizeof(int));
    int* cursor   = (int*)ws;  ws += align16((size_t)N * sizeof(int));
    int* csrc     = (int*)ws;  ws += align16((size_t)ET * sizeof(int));
    int* bsum     = (int*)ws;  ws += align16((size_t)NB * sizeof(int));
    int* boff     = (int*)ws;  ws += align16((size_t)NB * sizeof(int));
    float* h2 = h1;  // reuse h1 region after conv1 consumed it

    hipMemsetAsync(deg, 0, (size_t)N * sizeof(int), stream);
    hipMemsetAsync(cursor, 0, (size_t)N * sizeof(int), stream);

    int eb = (ET + 255) / 256;
    count_deg_k<<<eb, 256, 0, stream>>>(dstA, E, ET, deg);
    scan_a_k<<<NB, 256, 0, stream>>>(deg, N, rowstart, bsum);
    scan_b_k<<<1, 256, 0, stream>>>(bsum, NB, boff, rowstart + N);
    scan_c_k<<<(N + 255) / 256, 256, 0, stream>>>(rowstart, boff, N);
    scatter_k<<<eb, 256, 0, stream>>>(srcA, dstA, E, ET, rowstart, cursor, csrc);

    gemm1_k<<<(N + 127) / 128, 256, 0, stream>>>(x, W1, h1, N);
    score_k<<<(N * 4 + 255) / 256, 256, 0, stream>>>(h1, att1, s, N, 32);
    conv1_k<<<(N + 3) / 4, 256, 0, stream>>>(h1, s, rowstart, csrc, b1, helu, N);

    gemm2_k<<<(N + 7) / 8, 256, 0, stream>>>(helu, W2, h2, N);
    score_k<<<(N * 4 + 255) / 256, 256, 0, stream>>>(h2, att2, s, N, 8);
    int waves2 = (N + 1) / 2;
    conv2_k<<<(waves2 * 64 + 255) / 256, 256, 0, stream>>>(h2, s, rowstart, csrc, b2,
                                                           (float*)d_out, N);
}

// Round 4
// 272.799 us; speedup vs baseline: 1.8949x; 1.0687x over previous
//
#include <hip/hip_runtime.h>
#include <math.h>

// N=50000, E=800000, IN_DIM=256, H=4, HID=32 (conv1), OUT=8 (conv2).
// HDIM1=128, HDIM2=32.
//
// Softmax logit = si*sj + (1-si)(1-sj) in (0,1) -> exp can't overflow ->
// segment-max pass omitted (single-pass softmax).
//
// H1 and H2 feature matrices are stored in bf16 (f32 math) to halve the
// per-XCD compulsory gather traffic in conv1/conv2 (8 XCD private L2s each
// pull the whole table once for random gathers).

__device__ inline ushort f2bf(float f) {            // RNE f32->bf16
    uint u = __float_as_uint(f);
    return (ushort)((u + 0x7fffu + ((u >> 16) & 1u)) >> 16);
}
__device__ inline float bf_lo(uint u) { return __uint_as_float(u << 16); }
__device__ inline float bf_hi(uint u) { return __uint_as_float(u & 0xffff0000u); }

// ---------------- CSR build ----------------

__global__ void count_deg_k(const int* __restrict__ dstA, int E, int ET,
                            int* __restrict__ deg) {
    int e = blockIdx.x * blockDim.x + threadIdx.x;
    if (e >= ET) return;
    int d = (e < E) ? dstA[e] : (e - E);   // self-loop edges appended
    atomicAdd(&deg[d], 1);
}

__global__ __launch_bounds__(256) void scan_a_k(const int* __restrict__ deg, int n,
                                                int* __restrict__ rowstart,
                                                int* __restrict__ bsum) {
    __shared__ int ts[256];
    int t = threadIdx.x;
    int idx = blockIdx.x * 1024 + t * 4;
    int4 v = make_int4(0, 0, 0, 0);
    if (idx + 3 < n) {
        v = *(const int4*)(deg + idx);
    } else {
        if (idx < n)     v.x = deg[idx];
        if (idx + 1 < n) v.y = deg[idx + 1];
        if (idx + 2 < n) v.z = deg[idx + 2];
        if (idx + 3 < n) v.w = deg[idx + 3];
    }
    int s = v.x + v.y + v.z + v.w;
    ts[t] = s;
    __syncthreads();
#pragma unroll
    for (int off = 1; off < 256; off <<= 1) {
        int u = (t >= off) ? ts[t - off] : 0;
        __syncthreads();
        ts[t] += u;
        __syncthreads();
    }
    int excl = ts[t] - s;
    int p1 = excl + v.x, p2 = p1 + v.y, p3 = p2 + v.z;
    if (idx < n)     rowstart[idx]     = excl;
    if (idx + 1 < n) rowstart[idx + 1] = p1;
    if (idx + 2 < n) rowstart[idx + 2] = p2;
    if (idx + 3 < n) rowstart[idx + 3] = p3;
    if (t == 255) bsum[blockIdx.x] = ts[255];
}

__global__ __launch_bounds__(256) void scan_b_k(const int* __restrict__ bsum, int nb,
                                                int* __restrict__ boff,
                                                int* __restrict__ totalp) {
    __shared__ int ts[256];
    int t = threadIdx.x;
    int v = (t < nb) ? bsum[t] : 0;
    ts[t] = v;
    __syncthreads();
#pragma unroll
    for (int off = 1; off < 256; off <<= 1) {
        int u = (t >= off) ? ts[t - off] : 0;
        __syncthreads();
        ts[t] += u;
        __syncthreads();
    }
    if (t < nb) boff[t] = ts[t] - v;
    if (t == nb - 1) *totalp = ts[t];   // rowstart[N] = total edge count
}

__global__ void scan_c_k(int* __restrict__ rowstart, const int* __restrict__ boff,
                         int n) {
    int i = blockIdx.x * blockDim.x + threadIdx.x;
    if (i < n) rowstart[i] += boff[i >> 10];
}

__global__ void scatter_k(const int* __restrict__ srcA, const int* __restrict__ dstA,
                          int E, int ET, const int* __restrict__ rowstart,
                          int* __restrict__ cursor, int* __restrict__ csrc) {
    int e = blockIdx.x * blockDim.x + threadIdx.x;
    if (e >= ET) return;
    int d, s;
    if (e < E) { d = dstA[e]; s = srcA[e]; } else { d = e - E; s = e - E; }
    int pos = atomicAdd(&cursor[d], 1);
    csrc[rowstart[d] + pos] = s;   // store SRC node id directly
}

// ---------------- GEMM1: [N,256] @ [256,128] f32 -> bf16 H1 ----------------

__global__ __launch_bounds__(256) void gemm1_k(const float* __restrict__ X,
                                               const float* __restrict__ W,
                                               uint* __restrict__ H1b, int n) {
    __shared__ float As[16][128];   // transposed: [k][m]
    __shared__ float Bs[16][128];   // [k][n]
    int tid = threadIdx.x;
    int tx = tid & 15;     // 16 col-groups of 8
    int ty = tid >> 4;     // 16 row-groups of 8
    int brow = blockIdx.x * 128;
    float acc[8][8];
#pragma unroll
    for (int i = 0; i < 8; ++i)
#pragma unroll
        for (int j = 0; j < 8; ++j) acc[i][j] = 0.f;

    for (int k0 = 0; k0 < 256; k0 += 16) {
        {   // stage A tile (128 rows x 16 k), transposed into LDS
            int r = tid >> 1, kq = (tid & 1) * 8;
            int gr = brow + r;
            float4 av0, av1;
            if (gr < n) {
                av0 = *(const float4*)(X + (size_t)gr * 256 + k0 + kq);
                av1 = *(const float4*)(X + (size_t)gr * 256 + k0 + kq + 4);
            } else {
                av0 = av1 = make_float4(0.f, 0.f, 0.f, 0.f);
            }
            As[kq + 0][r] = av0.x; As[kq + 1][r] = av0.y;
            As[kq + 2][r] = av0.z; As[kq + 3][r] = av0.w;
            As[kq + 4][r] = av1.x; As[kq + 5][r] = av1.y;
            As[kq + 6][r] = av1.z; As[kq + 7][r] = av1.w;
        }
        {   // stage B tile (16 k x 128 cols)
            int idx = tid;
#pragma unroll
            for (int rep = 0; rep < 2; ++rep, idx += 256) {
                int kr = idx >> 5, cq = (idx & 31) * 4;
                *(float4*)&Bs[kr][cq] = *(const float4*)(W + (size_t)(k0 + kr) * 128 + cq);
            }
        }
        __syncthreads();
#pragma unroll
        for (int k = 0; k < 16; ++k) {
            float4 a0 = *(float4*)&As[k][ty * 8];
            float4 a1 = *(float4*)&As[k][ty * 8 + 4];
            float4 b0 = *(float4*)&Bs[k][tx * 8];
            float4 b1 = *(float4*)&Bs[k][tx * 8 + 4];
            float a[8] = {a0.x, a0.y, a0.z, a0.w, a1.x, a1.y, a1.z, a1.w};
            float b[8] = {b0.x, b0.y, b0.z, b0.w, b1.x, b1.y, b1.z, b1.w};
#pragma unroll
            for (int i = 0; i < 8; ++i)
#pragma unroll
                for (int j = 0; j < 8; ++j)
                    acc[i][j] = fmaf(a[i], b[j], acc[i][j]);
        }
        __syncthreads();
    }
#pragma unroll
    for (int i = 0; i < 8; ++i) {
        int gr = brow + ty * 8 + i;
        if (gr < n) {
            uint4 pk;
            pk.x = (uint)f2bf(acc[i][0]) | ((uint)f2bf(acc[i][1]) << 16);
            pk.y = (uint)f2bf(acc[i][2]) | ((uint)f2bf(acc[i][3]) << 16);
            pk.z = (uint)f2bf(acc[i][4]) | ((uint)f2bf(acc[i][5]) << 16);
            pk.w = (uint)f2bf(acc[i][6]) | ((uint)f2bf(acc[i][7]) << 16);
            *(uint4*)(H1b + (size_t)gr * 64 + tx * 4) = pk;
        }
    }
}

// ---------------- node scores from bf16 features ----------------
// cdim = 4*cph bf16 = 2*cph uints per row; per-head cph bf16 = cph/2 uints.

__global__ void score_k(const uint* __restrict__ Hb, const float* __restrict__ att,
                        float* __restrict__ S, int n, int cph) {
    int t = blockIdx.x * blockDim.x + threadIdx.x;
    if (t >= n * 4) return;
    int node = t >> 2, h = t & 3;
    const uint* row = Hb + (size_t)node * (cph * 2) + h * (cph / 2);
    const float* a = att + h * cph;
    float sum = 0.f;
    for (int c = 0; c < cph / 2; ++c) {
        uint u = row[c];
        sum = fmaf(bf_lo(u), a[2 * c], sum);
        sum = fmaf(bf_hi(u), a[2 * c + 1], sum);
    }
    S[t] = 1.f / (1.f + __expf(-sum));
}

// ---------------- conv1: wave per dst, bf16 gather (1 uint = 2ch / lane) ----

__global__ __launch_bounds__(256) void conv1_k(const uint* __restrict__ H1b,
                                               const float* __restrict__ S,
                                               const int* __restrict__ rowstart,
                                               const int* __restrict__ csrc,
                                               const float* __restrict__ b1,
                                               float* __restrict__ Hout, int n) {
    int wave = (int)((blockIdx.x * blockDim.x + threadIdx.x) >> 6);
    int lane = threadIdx.x & 63;
    if (wave >= n) return;
    int dst = wave;
    int hd = lane >> 4;            // 2 channels/lane -> head = (2*lane)/32
    float si = S[dst * 4 + hd];
    float omsi = 1.f - si;
    int rs = rowstart[dst], re = rowstart[dst + 1];

    float z0 = 0.f, z1 = 0.f, z2 = 0.f, z3 = 0.f;
    float x0 = 0.f, x1 = 0.f, x2 = 0.f, x3 = 0.f;
    float y0 = 0.f, y1 = 0.f, y2 = 0.f, y3 = 0.f;
    int i = rs;
    for (; i + 3 < re; i += 4) {
        int s0 = csrc[i], s1 = csrc[i + 1], s2 = csrc[i + 2], s3 = csrc[i + 3];
        float sj0 = S[s0 * 4 + hd], sj1 = S[s1 * 4 + hd];
        float sj2 = S[s2 * 4 + hd], sj3 = S[s3 * 4 + hd];
        uint u0 = H1b[(size_t)s0 * 64 + lane];
        uint u1 = H1b[(size_t)s1 * 64 + lane];
        uint u2 = H1b[(size_t)s2 * 64 + lane];
        uint u3 = H1b[(size_t)s3 * 64 + lane];
        float w0 = __expf(fmaf(si, sj0, omsi * (1.f - sj0)));
        float w1 = __expf(fmaf(si, sj1, omsi * (1.f - sj1)));
        float w2 = __expf(fmaf(si, sj2, omsi * (1.f - sj2)));
        float w3 = __expf(fmaf(si, sj3, omsi * (1.f - sj3)));
        z0 += w0; z1 += w1; z2 += w2; z3 += w3;
        x0 = fmaf(w0, bf_lo(u0), x0); x1 = fmaf(w1, bf_lo(u1), x1);
        x2 = fmaf(w2, bf_lo(u2), x2); x3 = fmaf(w3, bf_lo(u3), x3);
        y0 = fmaf(w0, bf_hi(u0), y0); y1 = fmaf(w1, bf_hi(u1), y1);
        y2 = fmaf(w2, bf_hi(u2), y2); y3 = fmaf(w3, bf_hi(u3), y3);
    }
    for (; i < re; ++i) {
        int s0 = csrc[i];
        float sj0 = S[s0 * 4 + hd];
        uint u0 = H1b[(size_t)s0 * 64 + lane];
        float w0 = __expf(fmaf(si, sj0, omsi * (1.f - sj0)));
        z0 += w0;
        x0 = fmaf(w0, bf_lo(u0), x0);
        y0 = fmaf(w0, bf_hi(u0), y0);
    }
    float inv = 1.f / ((z0 + z1) + (z2 + z3) + 1e-16f);
    float r0 = ((x0 + x1) + (x2 + x3)) * inv + b1[lane * 2];
    float r1 = ((y0 + y1) + (y2 + y3)) * inv + b1[lane * 2 + 1];
    r0 = (r0 > 0.f) ? r0 : (__expf(r0) - 1.f);   // ELU
    r1 = (r1 > 0.f) ? r1 : (__expf(r1) - 1.f);
    *(float2*)(Hout + (size_t)dst * 128 + lane * 2) = make_float2(r0, r1);
}

// ---------------- GEMM2: [N,128] @ [128,32] f32 -> bf16 H2 ----------------

__global__ __launch_bounds__(256) void gemm2_k(const float* __restrict__ Hin,
                                               const float* __restrict__ W2,
                                               ushort* __restrict__ H2b, int n) {
    __shared__ float rows[8][128];
    int tid = threadIdx.x;
    int node0 = blockIdx.x * 8;
    {
        int r = tid >> 5, q = (tid & 31) * 4;
        int gn = node0 + r;
        float4 v = (gn < n) ? *(const float4*)(Hin + (size_t)gn * 128 + q)
                            : make_float4(0.f, 0.f, 0.f, 0.f);
        *(float4*)&rows[r][q] = v;
    }
    __syncthreads();
    int r = tid >> 5;   // 0..7
    int c = tid & 31;   // 0..31
    int gn = node0 + r;
    if (gn >= n) return;
    float sum = 0.f;
#pragma unroll 4
    for (int k = 0; k < 128; ++k) sum = fmaf(rows[r][k], W2[k * 32 + c], sum);
    H2b[(size_t)gn * 32 + c] = f2bf(sum);
}

// ---------------- conv2: wave handles 2 dsts (32 lanes each), head-mean -----

__global__ __launch_bounds__(256) void conv2_k(const ushort* __restrict__ H2b,
                                               const float* __restrict__ S,
                                               const int* __restrict__ rowstart,
                                               const int* __restrict__ csrc,
                                               const float* __restrict__ b2,
                                               float* __restrict__ Out, int n) {
    int wave = (int)((blockIdx.x * blockDim.x + threadIdx.x) >> 6);
    int lane = threadIdx.x & 63;
    int half = lane >> 5;
    int c = lane & 31;             // channel = head*8 + o
    int dst = wave * 2 + half;
    if (dst >= n) return;
    int hd = c >> 3;
    float si = S[dst * 4 + hd];
    float omsi = 1.f - si;
    int rs = rowstart[dst], re = rowstart[dst + 1];

    float z0 = 0.f, z1 = 0.f, z2 = 0.f, z3 = 0.f;
    float a0 = 0.f, a1 = 0.f, a2 = 0.f, a3 = 0.f;
    int i = rs;
    for (; i + 3 < re; i += 4) {
        int s0 = csrc[i], s1 = csrc[i + 1], s2 = csrc[i + 2], s3 = csrc[i + 3];
        float sj0 = S[s0 * 4 + hd], sj1 = S[s1 * 4 + hd];
        float sj2 = S[s2 * 4 + hd], sj3 = S[s3 * 4 + hd];
        float v0 = __uint_as_float((uint)H2b[(size_t)s0 * 32 + c] << 16);
        float v1 = __uint_as_float((uint)H2b[(size_t)s1 * 32 + c] << 16);
        float v2 = __uint_as_float((uint)H2b[(size_t)s2 * 32 + c] << 16);
        float v3 = __uint_as_float((uint)H2b[(size_t)s3 * 32 + c] << 16);
        float w0 = __expf(fmaf(si, sj0, omsi * (1.f - sj0)));
        float w1 = __expf(fmaf(si, sj1, omsi * (1.f - sj1)));
        float w2 = __expf(fmaf(si, sj2, omsi * (1.f - sj2)));
        float w3 = __expf(fmaf(si, sj3, omsi * (1.f - sj3)));
        z0 += w0; a0 = fmaf(w0, v0, a0);
        z1 += w1; a1 = fmaf(w1, v1, a1);
        z2 += w2; a2 = fmaf(w2, v2, a2);
        z3 += w3; a3 = fmaf(w3, v3, a3);
    }
    for (; i < re; ++i) {
        int s0 = csrc[i];
        float sj0 = S[s0 * 4 + hd];
        float v0 = __uint_as_float((uint)H2b[(size_t)s0 * 32 + c] << 16);
        float w0 = __expf(fmaf(si, sj0, omsi * (1.f - sj0)));
        z0 += w0; a0 = fmaf(w0, v0, a0);
    }
    float r = ((a0 + a1) + (a2 + a3)) / (((z0 + z1) + (z2 + z3)) + 1e-16f);
    r += __shfl_xor(r, 8, 32);
    r += __shfl_xor(r, 16, 32);
    if (hd == 0) Out[(size_t)dst * 8 + c] = r * 0.25f + b2[c];
}

// ---------------- launcher ----------------

static inline size_t align16(size_t x) { return (x + 15) & ~(size_t)15; }

extern "C" void kernel_launch(void* const* d_in, const int* in_sizes, int n_in,
                              void* d_out, int out_size, void* d_ws, size_t ws_size,
                              hipStream_t stream) {
    const float* x    = (const float*)d_in[0];
    const int*   edge = (const int*)d_in[1];
    const float* W1   = (const float*)d_in[2];
    const float* att1 = (const float*)d_in[3];
    const float* b1   = (const float*)d_in[4];
    const float* W2   = (const float*)d_in[5];
    const float* att2 = (const float*)d_in[6];
    const float* b2   = (const float*)d_in[7];

    int N  = in_sizes[0] / 256;
    int E  = in_sizes[1] / 2;
    int ET = E + N;
    int NB = (N + 1023) / 1024;     // scan chunks
    const int* srcA = edge;
    const int* dstA = edge + E;

    // workspace layout (~46 MB), all carve-outs 16B-aligned
    char* ws = (char*)d_ws;
    uint*  h1b  = (uint*)ws;   ws += align16((size_t)N * 64 * sizeof(uint));   // bf16 x128
    float* helu = (float*)ws;  ws += align16((size_t)N * 128 * sizeof(float));
    ushort* h2b = (ushort*)ws; ws += align16((size_t)N * 32 * sizeof(ushort)); // bf16 x32
    float* s    = (float*)ws;  ws += align16((size_t)N * 4 * sizeof(float));
    int* rowstart = (int*)ws;  ws += align16((size_t)(N + 1) * sizeof(int));
    int* deg      = (int*)ws;  ws += align16((size_t)N * sizeof(int));
    int* cursor   = (int*)ws;  ws += align16((size_t)N * sizeof(int));
    int* csrc     = (int*)ws;  ws += align16((size_t)ET * sizeof(int));
    int* bsum     = (int*)ws;  ws += align16((size_t)NB * sizeof(int));
    int* boff     = (int*)ws;  ws += align16((size_t)NB * sizeof(int));

    hipMemsetAsync(deg, 0, (size_t)N * sizeof(int), stream);
    hipMemsetAsync(cursor, 0, (size_t)N * sizeof(int), stream);

    int eb = (ET + 255) / 256;
    count_deg_k<<<eb, 256, 0, stream>>>(dstA, E, ET, deg);
    scan_a_k<<<NB, 256, 0, stream>>>(deg, N, rowstart, bsum);
    scan_b_k<<<1, 256, 0, stream>>>(bsum, NB, boff, rowstart + N);
    scan_c_k<<<(N + 255) / 256, 256, 0, stream>>>(rowstart, boff, N);
    scatter_k<<<eb, 256, 0, stream>>>(srcA, dstA, E, ET, rowstart, cursor, csrc);

    gemm1_k<<<(N + 127) / 128, 256, 0, stream>>>(x, W1, h1b, N);
    score_k<<<(N * 4 + 255) / 256, 256, 0, stream>>>(h1b, att1, s, N, 32);
    conv1_k<<<(N + 3) / 4, 256, 0, stream>>>(h1b, s, rowstart, csrc, b1, helu, N);

    gemm2_k<<<(N + 7) / 8, 256, 0, stream>>>(helu, W2, h2b, N);
    score_k<<<(N * 4 + 255) / 256, 256, 0, stream>>>((const uint*)h2b, att2, s, N, 8);
    int waves2 = (N + 1) / 2;
    conv2_k<<<(waves2 * 64 + 255) / 256, 256, 0, stream>>>(h2b, s, rowstart, csrc, b2,
                                                           (float*)d_out, N);
}

// Round 5
// 237.870 us; speedup vs baseline: 2.1731x; 1.1468x over previous
//
#include <hip/hip_runtime.h>
#include <math.h>

// N=50000, E=800000, IN_DIM=256, H=4, HID=32 (conv1), OUT=8 (conv2).
// HDIM1=128, HDIM2=32.
//
// Softmax logit = si*sj + (1-si)(1-sj) in (0,1) -> exp can't overflow ->
// segment-max pass omitted (single-pass softmax).
//
// H1/H2 stored bf16 (f32 math) to halve per-XCD compulsory gather traffic.
// GEMM1 uses mfma_f32_16x16x32_bf16 (f32 accum), operands swapped so each
// lane's 4 accum regs are 4 consecutive OUTPUT COLUMNS of one row.

typedef __attribute__((ext_vector_type(8))) short bf16x8;
typedef __attribute__((ext_vector_type(4))) float f32x4;

__device__ inline ushort f2bf(float f) {            // RNE f32->bf16
    uint u = __float_as_uint(f);
    return (ushort)((u + 0x7fffu + ((u >> 16) & 1u)) >> 16);
}
__device__ inline float bf_lo(uint u) { return __uint_as_float(u << 16); }
__device__ inline float bf_hi(uint u) { return __uint_as_float(u & 0xffff0000u); }

// ---------------- CSR build ----------------

__global__ void count_deg_k(const int* __restrict__ dstA, int E, int ET,
                            int* __restrict__ deg) {
    int e = blockIdx.x * blockDim.x + threadIdx.x;
    if (e >= ET) return;
    int d = (e < E) ? dstA[e] : (e - E);   // self-loop edges appended
    atomicAdd(&deg[d], 1);
}

__global__ __launch_bounds__(256) void scan_a_k(const int* __restrict__ deg, int n,
                                                int* __restrict__ rowstart,
                                                int* __restrict__ bsum) {
    __shared__ int ts[256];
    int t = threadIdx.x;
    int idx = blockIdx.x * 1024 + t * 4;
    int4 v = make_int4(0, 0, 0, 0);
    if (idx + 3 < n) {
        v = *(const int4*)(deg + idx);
    } else {
        if (idx < n)     v.x = deg[idx];
        if (idx + 1 < n) v.y = deg[idx + 1];
        if (idx + 2 < n) v.z = deg[idx + 2];
        if (idx + 3 < n) v.w = deg[idx + 3];
    }
    int s = v.x + v.y + v.z + v.w;
    ts[t] = s;
    __syncthreads();
#pragma unroll
    for (int off = 1; off < 256; off <<= 1) {
        int u = (t >= off) ? ts[t - off] : 0;
        __syncthreads();
        ts[t] += u;
        __syncthreads();
    }
    int excl = ts[t] - s;
    int p1 = excl + v.x, p2 = p1 + v.y, p3 = p2 + v.z;
    if (idx < n)     rowstart[idx]     = excl;
    if (idx + 1 < n) rowstart[idx + 1] = p1;
    if (idx + 2 < n) rowstart[idx + 2] = p2;
    if (idx + 3 < n) rowstart[idx + 3] = p3;
    if (t == 255) bsum[blockIdx.x] = ts[255];
}

__global__ __launch_bounds__(256) void scan_b_k(const int* __restrict__ bsum, int nb,
                                                int* __restrict__ boff,
                                                int* __restrict__ totalp) {
    __shared__ int ts[256];
    int t = threadIdx.x;
    int v = (t < nb) ? bsum[t] : 0;
    ts[t] = v;
    __syncthreads();
#pragma unroll
    for (int off = 1; off < 256; off <<= 1) {
        int u = (t >= off) ? ts[t - off] : 0;
        __syncthreads();
        ts[t] += u;
        __syncthreads();
    }
    if (t < nb) boff[t] = ts[t] - v;
    if (t == nb - 1) *totalp = ts[t];   // rowstart[N] = total edge count
}

__global__ void scan_c_k(int* __restrict__ rowstart, const int* __restrict__ boff,
                         int n) {
    int i = blockIdx.x * blockDim.x + threadIdx.x;
    if (i < n) rowstart[i] += boff[i >> 10];
}

__global__ void scatter_k(const int* __restrict__ srcA, const int* __restrict__ dstA,
                          int E, int ET, const int* __restrict__ rowstart,
                          int* __restrict__ cursor, int* __restrict__ csrc) {
    int e = blockIdx.x * blockDim.x + threadIdx.x;
    if (e >= ET) return;
    int d, s;
    if (e < E) { d = dstA[e]; s = srcA[e]; } else { d = e - E; s = e - E; }
    int pos = atomicAdd(&cursor[d], 1);
    csrc[rowstart[d] + pos] = s;   // store SRC node id directly
}

// ---------------- W1 transpose+cvt: Wt[col][k] bf16 ----------------

__global__ void prep_wt_k(const float* __restrict__ W, ushort* __restrict__ Wt) {
    int idx = blockIdx.x * blockDim.x + threadIdx.x;
    if (idx >= 256 * 128) return;
    int k = idx >> 7, col = idx & 127;
    Wt[col * 256 + k] = f2bf(W[idx]);
}

// ---------------- GEMM1 (MFMA): [N,256] @ [256,128] -> bf16 H1 -------------
// 128x128 tile, BK=32, 4 waves x 32 rows. LDS frag layout [koct][row][8]bf16.
// acc[rt][ct] = mfma(Wfrag, Xfrag, acc): lane holds rows brow+rbase+(lane&15),
// cols ct*16 + (lane>>4)*4 + reg.

__global__ __launch_bounds__(256) void gemm1_k(const float* __restrict__ X,
                                               const ushort* __restrict__ Wt,
                                               uint* __restrict__ H1b, int n) {
    __shared__ __align__(16) ushort Alds[4][128][8];   // 8 KB  X tile
    __shared__ __align__(16) ushort Blds[4][128][8];   // 8 KB  W tile
    int tid = threadIdx.x;
    int wid = tid >> 6;
    int lane = tid & 63;
    int g = lane >> 4;        // k-octet
    int lr = lane & 15;
    int brow = blockIdx.x * 128;

    f32x4 acc[2][8];
#pragma unroll
    for (int rt = 0; rt < 2; ++rt)
#pragma unroll
        for (int ct = 0; ct < 8; ++ct) acc[rt][ct] = (f32x4){0.f, 0.f, 0.f, 0.f};

    for (int k0 = 0; k0 < 256; k0 += 32) {
        // stage X: 512 (r,koct) pairs, 2/thread; 8 f32 -> 8 bf16 (16B)
#pragma unroll
        for (int rep = 0; rep < 2; ++rep) {
            int idx = tid + rep * 256;
            int r = idx >> 2, koct = idx & 3;
            int gr = brow + r;
            float4 a0, a1;
            if (gr < n) {
                const float* p = X + (size_t)gr * 256 + k0 + koct * 8;
                a0 = *(const float4*)p;
                a1 = *(const float4*)(p + 4);
            } else {
                a0 = a1 = make_float4(0.f, 0.f, 0.f, 0.f);
            }
            uint4 pk;
            pk.x = (uint)f2bf(a0.x) | ((uint)f2bf(a0.y) << 16);
            pk.y = (uint)f2bf(a0.z) | ((uint)f2bf(a0.w) << 16);
            pk.z = (uint)f2bf(a1.x) | ((uint)f2bf(a1.y) << 16);
            pk.w = (uint)f2bf(a1.z) | ((uint)f2bf(a1.w) << 16);
            *(uint4*)&Alds[koct][r][0] = pk;
        }
        // stage W: 512 (koct,col) pairs, 2/thread; 16B bf16 copy
#pragma unroll
        for (int rep = 0; rep < 2; ++rep) {
            int idx = tid + rep * 256;
            int col = idx & 127, koct = idx >> 7;
            *(uint4*)&Blds[koct][col][0] =
                *(const uint4*)(Wt + (size_t)col * 256 + k0 + koct * 8);
        }
        __syncthreads();
        bf16x8 xf0 = *(bf16x8*)&Alds[g][wid * 32 + lr][0];
        bf16x8 xf1 = *(bf16x8*)&Alds[g][wid * 32 + 16 + lr][0];
#pragma unroll
        for (int ct = 0; ct < 8; ++ct) {
            bf16x8 wf = *(bf16x8*)&Blds[g][ct * 16 + lr][0];
            acc[0][ct] = __builtin_amdgcn_mfma_f32_16x16x32_bf16(wf, xf0, acc[0][ct], 0, 0, 0);
            acc[1][ct] = __builtin_amdgcn_mfma_f32_16x16x32_bf16(wf, xf1, acc[1][ct], 0, 0, 0);
        }
        __syncthreads();
    }
#pragma unroll
    for (int rt = 0; rt < 2; ++rt) {
        int row = brow + wid * 32 + rt * 16 + lr;
        if (row < n) {
#pragma unroll
            for (int ct = 0; ct < 8; ++ct) {
                uint lo = (uint)f2bf(acc[rt][ct][0]) | ((uint)f2bf(acc[rt][ct][1]) << 16);
                uint hi = (uint)f2bf(acc[rt][ct][2]) | ((uint)f2bf(acc[rt][ct][3]) << 16);
                *(uint2*)(H1b + (size_t)row * 64 + ct * 8 + g * 2) = make_uint2(lo, hi);
            }
        }
    }
}

// ---------------- node scores from bf16 features ----------------

__global__ void score_k(const uint* __restrict__ Hb, const float* __restrict__ att,
                        float* __restrict__ S, int n, int cph) {
    int t = blockIdx.x * blockDim.x + threadIdx.x;
    if (t >= n * 4) return;
    int node = t >> 2, h = t & 3;
    const uint* row = Hb + (size_t)node * (cph * 2) + h * (cph / 2);
    const float* a = att + h * cph;
    float sum = 0.f;
    for (int c = 0; c < cph / 2; ++c) {
        uint u = row[c];
        sum = fmaf(bf_lo(u), a[2 * c], sum);
        sum = fmaf(bf_hi(u), a[2 * c + 1], sum);
    }
    S[t] = 1.f / (1.f + __expf(-sum));
}

// ---------------- conv1: wave per dst, bf16 gather (1 uint = 2ch / lane) ----

__global__ __launch_bounds__(256) void conv1_k(const uint* __restrict__ H1b,
                                               const float* __restrict__ S,
                                               const int* __restrict__ rowstart,
                                               const int* __restrict__ csrc,
                                               const float* __restrict__ b1,
                                               float* __restrict__ Hout, int n) {
    int wave = (int)((blockIdx.x * blockDim.x + threadIdx.x) >> 6);
    int lane = threadIdx.x & 63;
    if (wave >= n) return;
    int dst = wave;
    int hd = lane >> 4;
    float si = S[dst * 4 + hd];
    float omsi = 1.f - si;
    int rs = rowstart[dst], re = rowstart[dst + 1];

    float z0 = 0.f, z1 = 0.f, z2 = 0.f, z3 = 0.f;
    float x0 = 0.f, x1 = 0.f, x2 = 0.f, x3 = 0.f;
    float y0 = 0.f, y1 = 0.f, y2 = 0.f, y3 = 0.f;
    int i = rs;
    for (; i + 3 < re; i += 4) {
        int s0 = csrc[i], s1 = csrc[i + 1], s2 = csrc[i + 2], s3 = csrc[i + 3];
        float sj0 = S[s0 * 4 + hd], sj1 = S[s1 * 4 + hd];
        float sj2 = S[s2 * 4 + hd], sj3 = S[s3 * 4 + hd];
        uint u0 = H1b[(size_t)s0 * 64 + lane];
        uint u1 = H1b[(size_t)s1 * 64 + lane];
        uint u2 = H1b[(size_t)s2 * 64 + lane];
        uint u3 = H1b[(size_t)s3 * 64 + lane];
        float w0 = __expf(fmaf(si, sj0, omsi * (1.f - sj0)));
        float w1 = __expf(fmaf(si, sj1, omsi * (1.f - sj1)));
        float w2 = __expf(fmaf(si, sj2, omsi * (1.f - sj2)));
        float w3 = __expf(fmaf(si, sj3, omsi * (1.f - sj3)));
        z0 += w0; z1 += w1; z2 += w2; z3 += w3;
        x0 = fmaf(w0, bf_lo(u0), x0); x1 = fmaf(w1, bf_lo(u1), x1);
        x2 = fmaf(w2, bf_lo(u2), x2); x3 = fmaf(w3, bf_lo(u3), x3);
        y0 = fmaf(w0, bf_hi(u0), y0); y1 = fmaf(w1, bf_hi(u1), y1);
        y2 = fmaf(w2, bf_hi(u2), y2); y3 = fmaf(w3, bf_hi(u3), y3);
    }
    for (; i < re; ++i) {
        int s0 = csrc[i];
        float sj0 = S[s0 * 4 + hd];
        uint u0 = H1b[(size_t)s0 * 64 + lane];
        float w0 = __expf(fmaf(si, sj0, omsi * (1.f - sj0)));
        z0 += w0;
        x0 = fmaf(w0, bf_lo(u0), x0);
        y0 = fmaf(w0, bf_hi(u0), y0);
    }
    float inv = 1.f / ((z0 + z1) + (z2 + z3) + 1e-16f);
    float r0 = ((x0 + x1) + (x2 + x3)) * inv + b1[lane * 2];
    float r1 = ((y0 + y1) + (y2 + y3)) * inv + b1[lane * 2 + 1];
    r0 = (r0 > 0.f) ? r0 : (__expf(r0) - 1.f);   // ELU
    r1 = (r1 > 0.f) ? r1 : (__expf(r1) - 1.f);
    *(float2*)(Hout + (size_t)dst * 128 + lane * 2) = make_float2(r0, r1);
}

// ---------------- GEMM2: [N,128] @ [128,32] f32 -> bf16 H2 ----------------

__global__ __launch_bounds__(256) void gemm2_k(const float* __restrict__ Hin,
                                               const float* __restrict__ W2,
                                               ushort* __restrict__ H2b, int n) {
    __shared__ float rows[8][128];
    int tid = threadIdx.x;
    int node0 = blockIdx.x * 8;
    {
        int r = tid >> 5, q = (tid & 31) * 4;
        int gn = node0 + r;
        float4 v = (gn < n) ? *(const float4*)(Hin + (size_t)gn * 128 + q)
                            : make_float4(0.f, 0.f, 0.f, 0.f);
        *(float4*)&rows[r][q] = v;
    }
    __syncthreads();
    int r = tid >> 5;
    int c = tid & 31;
    int gn = node0 + r;
    if (gn >= n) return;
    float sum = 0.f;
#pragma unroll 4
    for (int k = 0; k < 128; ++k) sum = fmaf(rows[r][k], W2[k * 32 + c], sum);
    H2b[(size_t)gn * 32 + c] = f2bf(sum);
}

// ---------------- conv2: wave handles 2 dsts (32 lanes each), head-mean -----

__global__ __launch_bounds__(256) void conv2_k(const ushort* __restrict__ H2b,
                                               const float* __restrict__ S,
                                               const int* __restrict__ rowstart,
                                               const int* __restrict__ csrc,
                                               const float* __restrict__ b2,
                                               float* __restrict__ Out, int n) {
    int wave = (int)((blockIdx.x * blockDim.x + threadIdx.x) >> 6);
    int lane = threadIdx.x & 63;
    int half = lane >> 5;
    int c = lane & 31;
    int dst = wave * 2 + half;
    if (dst >= n) return;
    int hd = c >> 3;
    float si = S[dst * 4 + hd];
    float omsi = 1.f - si;
    int rs = rowstart[dst], re = rowstart[dst + 1];

    float z0 = 0.f, z1 = 0.f, z2 = 0.f, z3 = 0.f;
    float a0 = 0.f, a1 = 0.f, a2 = 0.f, a3 = 0.f;
    int i = rs;
    for (; i + 3 < re; i += 4) {
        int s0 = csrc[i], s1 = csrc[i + 1], s2 = csrc[i + 2], s3 = csrc[i + 3];
        float sj0 = S[s0 * 4 + hd], sj1 = S[s1 * 4 + hd];
        float sj2 = S[s2 * 4 + hd], sj3 = S[s3 * 4 + hd];
        float v0 = __uint_as_float((uint)H2b[(size_t)s0 * 32 + c] << 16);
        float v1 = __uint_as_float((uint)H2b[(size_t)s1 * 32 + c] << 16);
        float v2 = __uint_as_float((uint)H2b[(size_t)s2 * 32 + c] << 16);
        float v3 = __uint_as_float((uint)H2b[(size_t)s3 * 32 + c] << 16);
        float w0 = __expf(fmaf(si, sj0, omsi * (1.f - sj0)));
        float w1 = __expf(fmaf(si, sj1, omsi * (1.f - sj1)));
        float w2 = __expf(fmaf(si, sj2, omsi * (1.f - sj2)));
        float w3 = __expf(fmaf(si, sj3, omsi * (1.f - sj3)));
        z0 += w0; a0 = fmaf(w0, v0, a0);
        z1 += w1; a1 = fmaf(w1, v1, a1);
        z2 += w2; a2 = fmaf(w2, v2, a2);
        z3 += w3; a3 = fmaf(w3, v3, a3);
    }
    for (; i < re; ++i) {
        int s0 = csrc[i];
        float sj0 = S[s0 * 4 + hd];
        float v0 = __uint_as_float((uint)H2b[(size_t)s0 * 32 + c] << 16);
        float w0 = __expf(fmaf(si, sj0, omsi * (1.f - sj0)));
        z0 += w0; a0 = fmaf(w0, v0, a0);
    }
    float r = ((a0 + a1) + (a2 + a3)) / (((z0 + z1) + (z2 + z3)) + 1e-16f);
    r += __shfl_xor(r, 8, 32);
    r += __shfl_xor(r, 16, 32);
    if (hd == 0) Out[(size_t)dst * 8 + c] = r * 0.25f + b2[c];
}

// ---------------- launcher ----------------

static inline size_t align16(size_t x) { return (x + 15) & ~(size_t)15; }

extern "C" void kernel_launch(void* const* d_in, const int* in_sizes, int n_in,
                              void* d_out, int out_size, void* d_ws, size_t ws_size,
                              hipStream_t stream) {
    const float* x    = (const float*)d_in[0];
    const int*   edge = (const int*)d_in[1];
    const float* W1   = (const float*)d_in[2];
    const float* att1 = (const float*)d_in[3];
    const float* b1   = (const float*)d_in[4];
    const float* W2   = (const float*)d_in[5];
    const float* att2 = (const float*)d_in[6];
    const float* b2   = (const float*)d_in[7];

    int N  = in_sizes[0] / 256;
    int E  = in_sizes[1] / 2;
    int ET = E + N;
    int NB = (N + 1023) / 1024;     // scan chunks
    const int* srcA = edge;
    const int* dstA = edge + E;

    // workspace layout (~46 MB), all carve-outs 16B-aligned
    char* ws = (char*)d_ws;
    uint*  h1b  = (uint*)ws;   ws += align16((size_t)N * 64 * sizeof(uint));   // bf16 x128
    float* helu = (float*)ws;  ws += align16((size_t)N * 128 * sizeof(float));
    ushort* h2b = (ushort*)ws; ws += align16((size_t)N * 32 * sizeof(ushort)); // bf16 x32
    float* s    = (float*)ws;  ws += align16((size_t)N * 4 * sizeof(float));
    int* rowstart = (int*)ws;  ws += align16((size_t)(N + 1) * sizeof(int));
    int* deg      = (int*)ws;  ws += align16((size_t)N * sizeof(int));
    int* cursor   = (int*)ws;  ws += align16((size_t)N * sizeof(int));
    int* csrc     = (int*)ws;  ws += align16((size_t)ET * sizeof(int));
    int* bsum     = (int*)ws;  ws += align16((size_t)NB * sizeof(int));
    int* boff     = (int*)ws;  ws += align16((size_t)NB * sizeof(int));
    ushort* w1t   = (ushort*)ws; ws += align16((size_t)256 * 128 * sizeof(ushort));

    hipMemsetAsync(deg, 0, (size_t)N * sizeof(int), stream);
    hipMemsetAsync(cursor, 0, (size_t)N * sizeof(int), stream);

    int eb = (ET + 255) / 256;
    count_deg_k<<<eb, 256, 0, stream>>>(dstA, E, ET, deg);
    scan_a_k<<<NB, 256, 0, stream>>>(deg, N, rowstart, bsum);
    scan_b_k<<<1, 256, 0, stream>>>(bsum, NB, boff, rowstart + N);
    scan_c_k<<<(N + 255) / 256, 256, 0, stream>>>(rowstart, boff, N);
    scatter_k<<<eb, 256, 0, stream>>>(srcA, dstA, E, ET, rowstart, cursor, csrc);

    prep_wt_k<<<(256 * 128 + 255) / 256, 256, 0, stream>>>(W1, w1t);
    gemm1_k<<<(N + 127) / 128, 256, 0, stream>>>(x, w1t, h1b, N);
    score_k<<<(N * 4 + 255) / 256, 256, 0, stream>>>(h1b, att1, s, N, 32);
    conv1_k<<<(N + 3) / 4, 256, 0, stream>>>(h1b, s, rowstart, csrc, b1, helu, N);

    gemm2_k<<<(N + 7) / 8, 256, 0, stream>>>(helu, W2, h2b, N);
    score_k<<<(N * 4 + 255) / 256, 256, 0, stream>>>((const uint*)h2b, att2, s, N, 8);
    int waves2 = (N + 1) / 2;
    conv2_k<<<(waves2 * 64 + 255) / 256, 256, 0, stream>>>(h2b, s, rowstart, csrc, b2,
                                                           (float*)d_out, N);
}

// Round 6
// 183.956 us; speedup vs baseline: 2.8100x; 1.2931x over previous
//
#include <hip/hip_runtime.h>
#include <math.h>

// N=50000, E=800000, IN_DIM=256, H=4, HID=32 (conv1), OUT=8 (conv2).
// HDIM1=128, HDIM2=32.
//
// Softmax logit = si*sj + (1-si)(1-sj) in (0,1) -> exp can't overflow ->
// segment-max pass omitted (single-pass softmax).
//
// H1/H2 stored bf16 (f32 math) to halve per-XCD compulsory gather traffic.
// GEMM1 = mfma_f32_16x16x32_bf16, swapped operands; score1 fused in its
// epilogue. conv1 fuses gemm2 (helu row @ W2 via LDS, split-k halves) and
// score2. CSR: csrc is ushort (N<65536); scatter has no atomics (positions
// precomputed in count pass).

typedef __attribute__((ext_vector_type(8))) short bf16x8;
typedef __attribute__((ext_vector_type(4))) float f32x4;

__device__ inline ushort f2bf(float f) {            // RNE f32->bf16
    uint u = __float_as_uint(f);
    return (ushort)((u + 0x7fffu + ((u >> 16) & 1u)) >> 16);
}
__device__ inline float bf_lo(uint u) { return __uint_as_float(u << 16); }
__device__ inline float bf_hi(uint u) { return __uint_as_float(u & 0xffff0000u); }

// ---------------- CSR build ----------------

__global__ void count_pos_k(const int* __restrict__ dstA, int E, int ET,
                            int* __restrict__ deg, ushort* __restrict__ epos) {
    int e = blockIdx.x * blockDim.x + threadIdx.x;
    if (e >= ET) return;
    int d = (e < E) ? dstA[e] : (e - E);   // self-loop edges appended
    epos[e] = (ushort)atomicAdd(&deg[d], 1);
}

__global__ __launch_bounds__(256) void scan_a_k(const int* __restrict__ deg, int n,
                                                int* __restrict__ rowstart,
                                                int* __restrict__ bsum) {
    __shared__ int ts[256];
    int t = threadIdx.x;
    int idx = blockIdx.x * 1024 + t * 4;
    int4 v = make_int4(0, 0, 0, 0);
    if (idx + 3 < n) {
        v = *(const int4*)(deg + idx);
    } else {
        if (idx < n)     v.x = deg[idx];
        if (idx + 1 < n) v.y = deg[idx + 1];
        if (idx + 2 < n) v.z = deg[idx + 2];
        if (idx + 3 < n) v.w = deg[idx + 3];
    }
    int s = v.x + v.y + v.z + v.w;
    ts[t] = s;
    __syncthreads();
#pragma unroll
    for (int off = 1; off < 256; off <<= 1) {
        int u = (t >= off) ? ts[t - off] : 0;
        __syncthreads();
        ts[t] += u;
        __syncthreads();
    }
    int excl = ts[t] - s;
    int p1 = excl + v.x, p2 = p1 + v.y, p3 = p2 + v.z;
    if (idx < n)     rowstart[idx]     = excl;
    if (idx + 1 < n) rowstart[idx + 1] = p1;
    if (idx + 2 < n) rowstart[idx + 2] = p2;
    if (idx + 3 < n) rowstart[idx + 3] = p3;
    if (t == 255) bsum[blockIdx.x] = ts[255];
}

__global__ __launch_bounds__(256) void scan_b_k(const int* __restrict__ bsum, int nb,
                                                int* __restrict__ boff,
                                                int* __restrict__ totalp) {
    __shared__ int ts[256];
    int t = threadIdx.x;
    int v = (t < nb) ? bsum[t] : 0;
    ts[t] = v;
    __syncthreads();
#pragma unroll
    for (int off = 1; off < 256; off <<= 1) {
        int u = (t >= off) ? ts[t - off] : 0;
        __syncthreads();
        ts[t] += u;
        __syncthreads();
    }
    if (t < nb) boff[t] = ts[t] - v;
    if (t == nb - 1) *totalp = ts[t];   // rowstart[N] = total edge count
}

__global__ void scan_c_k(int* __restrict__ rowstart, const int* __restrict__ boff,
                         int n) {
    int i = blockIdx.x * blockDim.x + threadIdx.x;
    if (i < n) rowstart[i] += boff[i >> 10];
}

__global__ void scatter_k(const int* __restrict__ srcA, const int* __restrict__ dstA,
                          int E, int ET, const int* __restrict__ rowstart,
                          const ushort* __restrict__ epos,
                          ushort* __restrict__ csrc) {
    int e = blockIdx.x * blockDim.x + threadIdx.x;
    if (e >= ET) return;
    int d, s;
    if (e < E) { d = dstA[e]; s = srcA[e]; } else { d = e - E; s = e - E; }
    csrc[rowstart[d] + epos[e]] = (ushort)s;
}

// ---------------- W1 transpose+cvt: Wt[col][k] bf16 ----------------

__global__ void prep_wt_k(const float* __restrict__ W, ushort* __restrict__ Wt) {
    int idx = blockIdx.x * blockDim.x + threadIdx.x;
    if (idx >= 256 * 128) return;
    int k = idx >> 7, col = idx & 127;
    Wt[col * 256 + k] = f2bf(W[idx]);
}

// ---------------- GEMM1 (MFMA) + fused score1 ----------------
// 128x128 tile, BK=32, 4 waves x 32 rows. acc[rt][ct]: lane holds row
// brow+wid*32+rt*16+(lane&15), cols ct*16+(lane>>4)*4+{0..3}.

__global__ __launch_bounds__(256) void gemm1_k(const float* __restrict__ X,
                                               const ushort* __restrict__ Wt,
                                               const float* __restrict__ ATT1,
                                               uint* __restrict__ H1b,
                                               float* __restrict__ S1, int n) {
    __shared__ __align__(16) ushort Alds[4][128][8];   // 8 KB  X tile
    __shared__ __align__(16) ushort Blds[4][128][8];   // 8 KB  W tile
    __shared__ float att1s[128];
    int tid = threadIdx.x;
    int wid = tid >> 6;
    int lane = tid & 63;
    int g = lane >> 4;        // k-octet
    int lr = lane & 15;
    int brow = blockIdx.x * 128;
    if (tid < 128) att1s[tid] = ATT1[tid];   // visible after first barrier

    f32x4 acc[2][8];
#pragma unroll
    for (int rt = 0; rt < 2; ++rt)
#pragma unroll
        for (int ct = 0; ct < 8; ++ct) acc[rt][ct] = (f32x4){0.f, 0.f, 0.f, 0.f};

    for (int k0 = 0; k0 < 256; k0 += 32) {
#pragma unroll
        for (int rep = 0; rep < 2; ++rep) {
            int idx = tid + rep * 256;
            int r = idx >> 2, koct = idx & 3;
            int gr = brow + r;
            float4 a0, a1;
            if (gr < n) {
                const float* p = X + (size_t)gr * 256 + k0 + koct * 8;
                a0 = *(const float4*)p;
                a1 = *(const float4*)(p + 4);
            } else {
                a0 = a1 = make_float4(0.f, 0.f, 0.f, 0.f);
            }
            uint4 pk;
            pk.x = (uint)f2bf(a0.x) | ((uint)f2bf(a0.y) << 16);
            pk.y = (uint)f2bf(a0.z) | ((uint)f2bf(a0.w) << 16);
            pk.z = (uint)f2bf(a1.x) | ((uint)f2bf(a1.y) << 16);
            pk.w = (uint)f2bf(a1.z) | ((uint)f2bf(a1.w) << 16);
            *(uint4*)&Alds[koct][r][0] = pk;
        }
#pragma unroll
        for (int rep = 0; rep < 2; ++rep) {
            int idx = tid + rep * 256;
            int col = idx & 127, koct = idx >> 7;
            *(uint4*)&Blds[koct][col][0] =
                *(const uint4*)(Wt + (size_t)col * 256 + k0 + koct * 8);
        }
        __syncthreads();
        bf16x8 xf0 = *(bf16x8*)&Alds[g][wid * 32 + lr][0];
        bf16x8 xf1 = *(bf16x8*)&Alds[g][wid * 32 + 16 + lr][0];
#pragma unroll
        for (int ct = 0; ct < 8; ++ct) {
            bf16x8 wf = *(bf16x8*)&Blds[g][ct * 16 + lr][0];
            acc[0][ct] = __builtin_amdgcn_mfma_f32_16x16x32_bf16(wf, xf0, acc[0][ct], 0, 0, 0);
            acc[1][ct] = __builtin_amdgcn_mfma_f32_16x16x32_bf16(wf, xf1, acc[1][ct], 0, 0, 0);
        }
        __syncthreads();
    }
#pragma unroll
    for (int rt = 0; rt < 2; ++rt) {
        int row = brow + wid * 32 + rt * 16 + lr;
        if (row < n) {
#pragma unroll
            for (int ct = 0; ct < 8; ++ct) {
                uint lo = (uint)f2bf(acc[rt][ct][0]) | ((uint)f2bf(acc[rt][ct][1]) << 16);
                uint hi = (uint)f2bf(acc[rt][ct][2]) | ((uint)f2bf(acc[rt][ct][3]) << 16);
                *(uint2*)(H1b + (size_t)row * 64 + ct * 8 + g * 2) = make_uint2(lo, hi);
            }
        }
        // fused score1: head h = ct>>1; att index = global col
        float sc[4] = {0.f, 0.f, 0.f, 0.f};
#pragma unroll
        for (int ct = 0; ct < 8; ++ct) {
            int base = ct * 16 + g * 4;
#pragma unroll
            for (int j = 0; j < 4; ++j)
                sc[ct >> 1] = fmaf(acc[rt][ct][j], att1s[base + j], sc[ct >> 1]);
        }
#pragma unroll
        for (int h = 0; h < 4; ++h) {
            sc[h] += __shfl_xor(sc[h], 16);
            sc[h] += __shfl_xor(sc[h], 32);
        }
        if (g == 0 && row < n) {
            float4 sv;
            sv.x = 1.f / (1.f + __expf(-sc[0]));
            sv.y = 1.f / (1.f + __expf(-sc[1]));
            sv.z = 1.f / (1.f + __expf(-sc[2]));
            sv.w = 1.f / (1.f + __expf(-sc[3]));
            *(float4*)(S1 + (size_t)row * 4) = sv;
        }
    }
}

// ---------------- conv1 + fused gemm2 + score2 ----------------
// wave per dst (4/block). Edge loop -> helu row in regs -> LDS row buffer ->
// split-k (two 32-lane halves) x 32 cols through W2 (LDS) -> h2 bf16 + score2.

__global__ __launch_bounds__(256) void conv1_k(const uint* __restrict__ H1b,
                                               const float* __restrict__ S1,
                                               const int* __restrict__ rowstart,
                                               const ushort* __restrict__ csrc,
                                               const float* __restrict__ b1,
                                               const float* __restrict__ W2,
                                               const float* __restrict__ ATT2,
                                               ushort* __restrict__ H2b,
                                               float* __restrict__ S2, int n) {
    __shared__ float w2s[128][32];     // 16 KB
    __shared__ float rowbuf[4][128];   // 2 KB
    __shared__ float att2s[32];
    int tid = threadIdx.x;
    for (int idx = tid; idx < 4096; idx += 256) ((float*)w2s)[idx] = W2[idx];
    if (tid < 32) att2s[tid] = ATT2[tid];
    __syncthreads();

    int wid = tid >> 6;
    int lane = tid & 63;
    int dst = blockIdx.x * 4 + wid;
    bool valid = dst < n;
    int hd = lane >> 4;
    float si = valid ? S1[dst * 4 + hd] : 0.f;
    float omsi = 1.f - si;
    int rs = 0, re = 0;
    if (valid) { rs = rowstart[dst]; re = rowstart[dst + 1]; }

    float z0 = 0.f, z1 = 0.f, z2 = 0.f, z3 = 0.f;
    float x0 = 0.f, x1 = 0.f, x2 = 0.f, x3 = 0.f;
    float y0 = 0.f, y1 = 0.f, y2 = 0.f, y3 = 0.f;
    int i = rs;
    for (; i + 3 < re; i += 4) {
        int s0 = csrc[i], s1 = csrc[i + 1], s2 = csrc[i + 2], s3 = csrc[i + 3];
        float sj0 = S1[s0 * 4 + hd], sj1 = S1[s1 * 4 + hd];
        float sj2 = S1[s2 * 4 + hd], sj3 = S1[s3 * 4 + hd];
        uint u0 = H1b[(size_t)s0 * 64 + lane];
        uint u1 = H1b[(size_t)s1 * 64 + lane];
        uint u2 = H1b[(size_t)s2 * 64 + lane];
        uint u3 = H1b[(size_t)s3 * 64 + lane];
        float w0 = __expf(fmaf(si, sj0, omsi * (1.f - sj0)));
        float w1 = __expf(fmaf(si, sj1, omsi * (1.f - sj1)));
        float w2 = __expf(fmaf(si, sj2, omsi * (1.f - sj2)));
        float w3 = __expf(fmaf(si, sj3, omsi * (1.f - sj3)));
        z0 += w0; z1 += w1; z2 += w2; z3 += w3;
        x0 = fmaf(w0, bf_lo(u0), x0); x1 = fmaf(w1, bf_lo(u1), x1);
        x2 = fmaf(w2, bf_lo(u2), x2); x3 = fmaf(w3, bf_lo(u3), x3);
        y0 = fmaf(w0, bf_hi(u0), y0); y1 = fmaf(w1, bf_hi(u1), y1);
        y2 = fmaf(w2, bf_hi(u2), y2); y3 = fmaf(w3, bf_hi(u3), y3);
    }
    for (; i < re; ++i) {
        int s0 = csrc[i];
        float sj0 = S1[s0 * 4 + hd];
        uint u0 = H1b[(size_t)s0 * 64 + lane];
        float w0 = __expf(fmaf(si, sj0, omsi * (1.f - sj0)));
        z0 += w0;
        x0 = fmaf(w0, bf_lo(u0), x0);
        y0 = fmaf(w0, bf_hi(u0), y0);
    }
    float inv = 1.f / ((z0 + z1) + (z2 + z3) + 1e-16f);
    float r0 = ((x0 + x1) + (x2 + x3)) * inv + b1[lane * 2];
    float r1 = ((y0 + y1) + (y2 + y3)) * inv + b1[lane * 2 + 1];
    r0 = (r0 > 0.f) ? r0 : (__expf(r0) - 1.f);   // ELU
    r1 = (r1 > 0.f) ? r1 : (__expf(r1) - 1.f);

    // fused gemm2: wave-local LDS row, split-k across halves
    *(float2*)&rowbuf[wid][lane * 2] = make_float2(r0, r1);
    int half = lane >> 5, c = lane & 31;
    const float* rb = &rowbuf[wid][half * 64];
    float sum = 0.f;
#pragma unroll
    for (int k = 0; k < 64; k += 4) {
        float4 rv = *(const float4*)(rb + k);
        sum = fmaf(rv.x, w2s[half * 64 + k + 0][c], sum);
        sum = fmaf(rv.y, w2s[half * 64 + k + 1][c], sum);
        sum = fmaf(rv.z, w2s[half * 64 + k + 2][c], sum);
        sum = fmaf(rv.w, w2s[half * 64 + k + 3][c], sum);
    }
    sum += __shfl_xor(sum, 32);
    if (valid && half == 0) H2b[(size_t)dst * 32 + c] = f2bf(sum);

    // fused score2: head = c>>3
    float v = sum * att2s[c];
    v += __shfl_xor(v, 1);
    v += __shfl_xor(v, 2);
    v += __shfl_xor(v, 4);
    if (valid && half == 0 && (c & 7) == 0)
        S2[dst * 4 + (c >> 3)] = 1.f / (1.f + __expf(-v));
}

// ---------------- conv2: wave handles 2 dsts (32 lanes each), head-mean -----

__global__ __launch_bounds__(256) void conv2_k(const ushort* __restrict__ H2b,
                                               const float* __restrict__ S,
                                               const int* __restrict__ rowstart,
                                               const ushort* __restrict__ csrc,
                                               const float* __restrict__ b2,
                                               float* __restrict__ Out, int n) {
    int wave = (int)((blockIdx.x * blockDim.x + threadIdx.x) >> 6);
    int lane = threadIdx.x & 63;
    int half = lane >> 5;
    int c = lane & 31;
    int dst = wave * 2 + half;
    if (dst >= n) return;
    int hd = c >> 3;
    float si = S[dst * 4 + hd];
    float omsi = 1.f - si;
    int rs = rowstart[dst], re = rowstart[dst + 1];

    float z0 = 0.f, z1 = 0.f, z2 = 0.f, z3 = 0.f;
    float a0 = 0.f, a1 = 0.f, a2 = 0.f, a3 = 0.f;
    int i = rs;
    for (; i + 3 < re; i += 4) {
        int s0 = csrc[i], s1 = csrc[i + 1], s2 = csrc[i + 2], s3 = csrc[i + 3];
        float sj0 = S[s0 * 4 + hd], sj1 = S[s1 * 4 + hd];
        float sj2 = S[s2 * 4 + hd], sj3 = S[s3 * 4 + hd];
        float v0 = __uint_as_float((uint)H2b[(size_t)s0 * 32 + c] << 16);
        float v1 = __uint_as_float((uint)H2b[(size_t)s1 * 32 + c] << 16);
        float v2 = __uint_as_float((uint)H2b[(size_t)s2 * 32 + c] << 16);
        float v3 = __uint_as_float((uint)H2b[(size_t)s3 * 32 + c] << 16);
        float w0 = __expf(fmaf(si, sj0, omsi * (1.f - sj0)));
        float w1 = __expf(fmaf(si, sj1, omsi * (1.f - sj1)));
        float w2 = __expf(fmaf(si, sj2, omsi * (1.f - sj2)));
        float w3 = __expf(fmaf(si, sj3, omsi * (1.f - sj3)));
        z0 += w0; a0 = fmaf(w0, v0, a0);
        z1 += w1; a1 = fmaf(w1, v1, a1);
        z2 += w2; a2 = fmaf(w2, v2, a2);
        z3 += w3; a3 = fmaf(w3, v3, a3);
    }
    for (; i < re; ++i) {
        int s0 = csrc[i];
        float sj0 = S[s0 * 4 + hd];
        float v0 = __uint_as_float((uint)H2b[(size_t)s0 * 32 + c] << 16);
        float w0 = __expf(fmaf(si, sj0, omsi * (1.f - sj0)));
        z0 += w0; a0 = fmaf(w0, v0, a0);
    }
    float r = ((a0 + a1) + (a2 + a3)) / (((z0 + z1) + (z2 + z3)) + 1e-16f);
    r += __shfl_xor(r, 8, 32);
    r += __shfl_xor(r, 16, 32);
    if (hd == 0) Out[(size_t)dst * 8 + c] = r * 0.25f + b2[c];
}

// ---------------- launcher ----------------

static inline size_t align16(size_t x) { return (x + 15) & ~(size_t)15; }

extern "C" void kernel_launch(void* const* d_in, const int* in_sizes, int n_in,
                              void* d_out, int out_size, void* d_ws, size_t ws_size,
                              hipStream_t stream) {
    const float* x    = (const float*)d_in[0];
    const int*   edge = (const int*)d_in[1];
    const float* W1   = (const float*)d_in[2];
    const float* att1 = (const float*)d_in[3];
    const float* b1   = (const float*)d_in[4];
    const float* W2   = (const float*)d_in[5];
    const float* att2 = (const float*)d_in[6];
    const float* b2   = (const float*)d_in[7];

    int N  = in_sizes[0] / 256;
    int E  = in_sizes[1] / 2;
    int ET = E + N;
    int NB = (N + 1023) / 1024;     // scan chunks
    const int* srcA = edge;
    const int* dstA = edge + E;

    // workspace layout (~21 MB), all carve-outs 16B-aligned
    char* ws = (char*)d_ws;
    uint*  h1b  = (uint*)ws;   ws += align16((size_t)N * 64 * sizeof(uint));   // bf16 x128
    ushort* h2b = (ushort*)ws; ws += align16((size_t)N * 32 * sizeof(ushort)); // bf16 x32
    float* s1   = (float*)ws;  ws += align16((size_t)N * 4 * sizeof(float));
    float* s2   = (float*)ws;  ws += align16((size_t)N * 4 * sizeof(float));
    int* rowstart = (int*)ws;  ws += align16((size_t)(N + 1) * sizeof(int));
    int* deg      = (int*)ws;  ws += align16((size_t)N * sizeof(int));
    ushort* csrc  = (ushort*)ws; ws += align16((size_t)ET * sizeof(ushort));
    ushort* epos  = (ushort*)ws; ws += align16((size_t)ET * sizeof(ushort));
    int* bsum     = (int*)ws;  ws += align16((size_t)NB * sizeof(int));
    int* boff     = (int*)ws;  ws += align16((size_t)NB * sizeof(int));
    ushort* w1t   = (ushort*)ws; ws += align16((size_t)256 * 128 * sizeof(ushort));

    hipMemsetAsync(deg, 0, (size_t)N * sizeof(int), stream);

    int eb = (ET + 255) / 256;
    count_pos_k<<<eb, 256, 0, stream>>>(dstA, E, ET, deg, epos);
    scan_a_k<<<NB, 256, 0, stream>>>(deg, N, rowstart, bsum);
    scan_b_k<<<1, 256, 0, stream>>>(bsum, NB, boff, rowstart + N);
    scan_c_k<<<(N + 255) / 256, 256, 0, stream>>>(rowstart, boff, N);
    scatter_k<<<eb, 256, 0, stream>>>(srcA, dstA, E, ET, rowstart, epos, csrc);

    prep_wt_k<<<(256 * 128 + 255) / 256, 256, 0, stream>>>(W1, w1t);
    gemm1_k<<<(N + 127) / 128, 256, 0, stream>>>(x, w1t, att1, h1b, s1, N);
    conv1_k<<<(N + 3) / 4, 256, 0, stream>>>(h1b, s1, rowstart, csrc, b1, W2, att2,
                                             h2b, s2, N);
    int waves2 = (N + 1) / 2;
    conv2_k<<<(waves2 * 64 + 255) / 256, 256, 0, stream>>>(h2b, s2, rowstart, csrc, b2,
                                                           (float*)d_out, N);
}

// Round 7
// 160.749 us; speedup vs baseline: 3.2157x; 1.1444x over previous
//
#include <hip/hip_runtime.h>
#include <math.h>

// N=50000, E=800000, IN_DIM=256, H=4, HID=32 (conv1), OUT=8 (conv2).
// HDIM1=128, HDIM2=32.
//
// Softmax logit = si*sj + (1-si)(1-sj) in (0,1) -> exp can't overflow ->
// segment-max pass omitted (single-pass softmax).
//
// H1/H2 stored bf16 (f32 math). GEMM1 = mfma_f32_16x16x32_bf16 with fused
// score1. conv1: phase-A computes per-edge weights (1 exp per edge-head,
// lanes=edges) into LDS; phase-B is a lean channel-gather; fused gemm2
// (transposed W2 in LDS, float4 reads) + score2. conv2: 16 lanes/dst,
// 4 dsts/wave. CSR: ushort csrc, atomic-free scatter.

typedef __attribute__((ext_vector_type(8))) short bf16x8;
typedef __attribute__((ext_vector_type(4))) float f32x4;

__device__ inline ushort f2bf(float f) {            // RNE f32->bf16
    uint u = __float_as_uint(f);
    return (ushort)((u + 0x7fffu + ((u >> 16) & 1u)) >> 16);
}
__device__ inline float bf_lo(uint u) { return __uint_as_float(u << 16); }
__device__ inline float bf_hi(uint u) { return __uint_as_float(u & 0xffff0000u); }

// ---------------- CSR build ----------------

__global__ void count_pos_k(const int* __restrict__ dstA, int E, int ET,
                            int* __restrict__ deg, ushort* __restrict__ epos) {
    int e = blockIdx.x * blockDim.x + threadIdx.x;
    if (e >= ET) return;
    int d = (e < E) ? dstA[e] : (e - E);   // self-loop edges appended
    epos[e] = (ushort)atomicAdd(&deg[d], 1);
}

__global__ __launch_bounds__(256) void scan_a_k(const int* __restrict__ deg, int n,
                                                int* __restrict__ rowstart,
                                                int* __restrict__ bsum) {
    __shared__ int ts[256];
    int t = threadIdx.x;
    int idx = blockIdx.x * 1024 + t * 4;
    int4 v = make_int4(0, 0, 0, 0);
    if (idx + 3 < n) {
        v = *(const int4*)(deg + idx);
    } else {
        if (idx < n)     v.x = deg[idx];
        if (idx + 1 < n) v.y = deg[idx + 1];
        if (idx + 2 < n) v.z = deg[idx + 2];
        if (idx + 3 < n) v.w = deg[idx + 3];
    }
    int s = v.x + v.y + v.z + v.w;
    ts[t] = s;
    __syncthreads();
#pragma unroll
    for (int off = 1; off < 256; off <<= 1) {
        int u = (t >= off) ? ts[t - off] : 0;
        __syncthreads();
        ts[t] += u;
        __syncthreads();
    }
    int excl = ts[t] - s;
    int p1 = excl + v.x, p2 = p1 + v.y, p3 = p2 + v.z;
    if (idx < n)     rowstart[idx]     = excl;
    if (idx + 1 < n) rowstart[idx + 1] = p1;
    if (idx + 2 < n) rowstart[idx + 2] = p2;
    if (idx + 3 < n) rowstart[idx + 3] = p3;
    if (t == 255) bsum[blockIdx.x] = ts[255];
}

__global__ __launch_bounds__(256) void scan_b_k(const int* __restrict__ bsum, int nb,
                                                int* __restrict__ boff,
                                                int* __restrict__ totalp) {
    __shared__ int ts[256];
    int t = threadIdx.x;
    int v = (t < nb) ? bsum[t] : 0;
    ts[t] = v;
    __syncthreads();
#pragma unroll
    for (int off = 1; off < 256; off <<= 1) {
        int u = (t >= off) ? ts[t - off] : 0;
        __syncthreads();
        ts[t] += u;
        __syncthreads();
    }
    if (t < nb) boff[t] = ts[t] - v;
    if (t == nb - 1) *totalp = ts[t];
}

__global__ void scan_c_k(int* __restrict__ rowstart, const int* __restrict__ boff,
                         int n) {
    int i = blockIdx.x * blockDim.x + threadIdx.x;
    if (i < n) rowstart[i] += boff[i >> 10];
}

__global__ void scatter_k(const int* __restrict__ srcA, const int* __restrict__ dstA,
                          int E, int ET, const int* __restrict__ rowstart,
                          const ushort* __restrict__ epos,
                          ushort* __restrict__ csrc) {
    int e = blockIdx.x * blockDim.x + threadIdx.x;
    if (e >= ET) return;
    int d, s;
    if (e < E) { d = dstA[e]; s = srcA[e]; } else { d = e - E; s = e - E; }
    csrc[rowstart[d] + epos[e]] = (ushort)s;
}

// ---------------- W1 transpose+cvt: Wt[col][k] bf16 ----------------

__global__ void prep_wt_k(const float* __restrict__ W, ushort* __restrict__ Wt) {
    int idx = blockIdx.x * blockDim.x + threadIdx.x;
    if (idx >= 256 * 128) return;
    int k = idx >> 7, col = idx & 127;
    Wt[col * 256 + k] = f2bf(W[idx]);
}

// ---------------- GEMM1 (MFMA) + fused score1 ----------------

__global__ __launch_bounds__(256) void gemm1_k(const float* __restrict__ X,
                                               const ushort* __restrict__ Wt,
                                               const float* __restrict__ ATT1,
                                               uint* __restrict__ H1b,
                                               float* __restrict__ S1, int n) {
    __shared__ __align__(16) ushort Alds[4][128][8];
    __shared__ __align__(16) ushort Blds[4][128][8];
    __shared__ float att1s[128];
    int tid = threadIdx.x;
    int wid = tid >> 6;
    int lane = tid & 63;
    int g = lane >> 4;
    int lr = lane & 15;
    int brow = blockIdx.x * 128;
    if (tid < 128) att1s[tid] = ATT1[tid];

    f32x4 acc[2][8];
#pragma unroll
    for (int rt = 0; rt < 2; ++rt)
#pragma unroll
        for (int ct = 0; ct < 8; ++ct) acc[rt][ct] = (f32x4){0.f, 0.f, 0.f, 0.f};

    for (int k0 = 0; k0 < 256; k0 += 32) {
#pragma unroll
        for (int rep = 0; rep < 2; ++rep) {
            int idx = tid + rep * 256;
            int r = idx >> 2, koct = idx & 3;
            int gr = brow + r;
            float4 a0, a1;
            if (gr < n) {
                const float* p = X + (size_t)gr * 256 + k0 + koct * 8;
                a0 = *(const float4*)p;
                a1 = *(const float4*)(p + 4);
            } else {
                a0 = a1 = make_float4(0.f, 0.f, 0.f, 0.f);
            }
            uint4 pk;
            pk.x = (uint)f2bf(a0.x) | ((uint)f2bf(a0.y) << 16);
            pk.y = (uint)f2bf(a0.z) | ((uint)f2bf(a0.w) << 16);
            pk.z = (uint)f2bf(a1.x) | ((uint)f2bf(a1.y) << 16);
            pk.w = (uint)f2bf(a1.z) | ((uint)f2bf(a1.w) << 16);
            *(uint4*)&Alds[koct][r][0] = pk;
        }
#pragma unroll
        for (int rep = 0; rep < 2; ++rep) {
            int idx = tid + rep * 256;
            int col = idx & 127, koct = idx >> 7;
            *(uint4*)&Blds[koct][col][0] =
                *(const uint4*)(Wt + (size_t)col * 256 + k0 + koct * 8);
        }
        __syncthreads();
        bf16x8 xf0 = *(bf16x8*)&Alds[g][wid * 32 + lr][0];
        bf16x8 xf1 = *(bf16x8*)&Alds[g][wid * 32 + 16 + lr][0];
#pragma unroll
        for (int ct = 0; ct < 8; ++ct) {
            bf16x8 wf = *(bf16x8*)&Blds[g][ct * 16 + lr][0];
            acc[0][ct] = __builtin_amdgcn_mfma_f32_16x16x32_bf16(wf, xf0, acc[0][ct], 0, 0, 0);
            acc[1][ct] = __builtin_amdgcn_mfma_f32_16x16x32_bf16(wf, xf1, acc[1][ct], 0, 0, 0);
        }
        __syncthreads();
    }
#pragma unroll
    for (int rt = 0; rt < 2; ++rt) {
        int row = brow + wid * 32 + rt * 16 + lr;
        if (row < n) {
#pragma unroll
            for (int ct = 0; ct < 8; ++ct) {
                uint lo = (uint)f2bf(acc[rt][ct][0]) | ((uint)f2bf(acc[rt][ct][1]) << 16);
                uint hi = (uint)f2bf(acc[rt][ct][2]) | ((uint)f2bf(acc[rt][ct][3]) << 16);
                *(uint2*)(H1b + (size_t)row * 64 + ct * 8 + g * 2) = make_uint2(lo, hi);
            }
        }
        float sc[4] = {0.f, 0.f, 0.f, 0.f};
#pragma unroll
        for (int ct = 0; ct < 8; ++ct) {
            int base = ct * 16 + g * 4;
#pragma unroll
            for (int j = 0; j < 4; ++j)
                sc[ct >> 1] = fmaf(acc[rt][ct][j], att1s[base + j], sc[ct >> 1]);
        }
#pragma unroll
        for (int h = 0; h < 4; ++h) {
            sc[h] += __shfl_xor(sc[h], 16);
            sc[h] += __shfl_xor(sc[h], 32);
        }
        if (g == 0 && row < n) {
            float4 sv;
            sv.x = 1.f / (1.f + __expf(-sc[0]));
            sv.y = 1.f / (1.f + __expf(-sc[1]));
            sv.z = 1.f / (1.f + __expf(-sc[2]));
            sv.w = 1.f / (1.f + __expf(-sc[3]));
            *(float4*)(S1 + (size_t)row * 4) = sv;
        }
    }
}

// ---------------- conv1 + fused gemm2 + score2 ----------------
// 512 threads = 8 waves, wave per dst. Chunked edge loop:
//   phase A (lanes=edges): 1 exp per (edge,head), w[4]+src -> LDS
//   phase B (lanes=channels): LDS w broadcast + readfirstlane src + gather.

__global__ __launch_bounds__(512) void conv1_k(const uint* __restrict__ H1b,
                                               const float* __restrict__ S1,
                                               const int* __restrict__ rowstart,
                                               const ushort* __restrict__ csrc,
                                               const float* __restrict__ b1,
                                               const float* __restrict__ W2,
                                               const float* __restrict__ ATT2,
                                               ushort* __restrict__ H2b,
                                               float* __restrict__ S2, int n) {
    __shared__ float w2t[32][132];     // transposed W2, padded (16.9 KB)
    __shared__ float rowbuf[8][128];   // 4 KB
    __shared__ float wbuf[8][32][4];   // 4 KB  per-edge weights (chunk of 32)
    __shared__ ushort srcs[8][32];     // 0.5 KB
    __shared__ float att2s[32];
    int tid = threadIdx.x;
    for (int idx = tid; idx < 4096; idx += 512) {
        int k = idx >> 5, c = idx & 31;
        w2t[c][k] = W2[idx];
    }
    if (tid < 32) att2s[tid] = ATT2[tid];
    __syncthreads();

    int wid = tid >> 6;
    int lane = tid & 63;
    int dst = blockIdx.x * 8 + wid;
    bool valid = dst < n;
    int hd = lane >> 4;
    float4 si4 = valid ? *(const float4*)(S1 + (size_t)dst * 4)
                       : make_float4(0.f, 0.f, 0.f, 0.f);
    int rs = 0, re = 0;
    if (valid) { rs = rowstart[dst]; re = rowstart[dst + 1]; }

    float z0 = 0.f, z1 = 0.f, z2 = 0.f, z3 = 0.f;
    float x0 = 0.f, x1 = 0.f, x2 = 0.f, x3 = 0.f;
    float y0 = 0.f, y1 = 0.f, y2 = 0.f, y3 = 0.f;

    for (int cb = rs; cb < re; cb += 32) {
        int cnt = min(32, re - cb);
        // ---- phase A: per-edge weights (all 4 heads), lanes = edges ----
        if (lane < cnt) {
            int s = csrc[cb + lane];
            float4 sj = *(const float4*)(S1 + (size_t)s * 4);
            float w0 = __expf(fmaf(si4.x, sj.x, (1.f - si4.x) * (1.f - sj.x)));
            float w1 = __expf(fmaf(si4.y, sj.y, (1.f - si4.y) * (1.f - sj.y)));
            float w2 = __expf(fmaf(si4.z, sj.z, (1.f - si4.z) * (1.f - sj.z)));
            float w3 = __expf(fmaf(si4.w, sj.w, (1.f - si4.w) * (1.f - sj.w)));
            *(float4*)&wbuf[wid][lane][0] = make_float4(w0, w1, w2, w3);
            srcs[wid][lane] = (ushort)s;
        }
        asm volatile("s_waitcnt lgkmcnt(0)" ::: "memory");  // A -> B (same wave)
        // ---- phase B: channel gather ----
        int e = 0;
        for (; e + 3 < cnt; e += 4) {
            int sA = (int)srcs[wid][e];
            int sB = (int)srcs[wid][e + 1];
            int sC = (int)srcs[wid][e + 2];
            int sD = (int)srcs[wid][e + 3];
            sA = __builtin_amdgcn_readfirstlane(sA);
            sB = __builtin_amdgcn_readfirstlane(sB);
            sC = __builtin_amdgcn_readfirstlane(sC);
            sD = __builtin_amdgcn_readfirstlane(sD);
            float wA = wbuf[wid][e][hd];
            float wB = wbuf[wid][e + 1][hd];
            float wC = wbuf[wid][e + 2][hd];
            float wD = wbuf[wid][e + 3][hd];
            uint uA = H1b[(size_t)sA * 64 + lane];
            uint uB = H1b[(size_t)sB * 64 + lane];
            uint uC = H1b[(size_t)sC * 64 + lane];
            uint uD = H1b[(size_t)sD * 64 + lane];
            z0 += wA; z1 += wB; z2 += wC; z3 += wD;
            x0 = fmaf(wA, bf_lo(uA), x0); x1 = fmaf(wB, bf_lo(uB), x1);
            x2 = fmaf(wC, bf_lo(uC), x2); x3 = fmaf(wD, bf_lo(uD), x3);
            y0 = fmaf(wA, bf_hi(uA), y0); y1 = fmaf(wB, bf_hi(uB), y1);
            y2 = fmaf(wC, bf_hi(uC), y2); y3 = fmaf(wD, bf_hi(uD), y3);
        }
        for (; e < cnt; ++e) {
            int s = (int)srcs[wid][e];
            s = __builtin_amdgcn_readfirstlane(s);
            float w = wbuf[wid][e][hd];
            uint u = H1b[(size_t)s * 64 + lane];
            z0 += w;
            x0 = fmaf(w, bf_lo(u), x0);
            y0 = fmaf(w, bf_hi(u), y0);
        }
        asm volatile("" ::: "memory");  // keep next A's writes after B's reads
    }
    float inv = 1.f / ((z0 + z1) + (z2 + z3) + 1e-16f);
    float r0 = ((x0 + x1) + (x2 + x3)) * inv + b1[lane * 2];
    float r1 = ((y0 + y1) + (y2 + y3)) * inv + b1[lane * 2 + 1];
    r0 = (r0 > 0.f) ? r0 : (__expf(r0) - 1.f);   // ELU
    r1 = (r1 > 0.f) ? r1 : (__expf(r1) - 1.f);

    // fused gemm2: split-k across wave halves, float4 LDS reads
    *(float2*)&rowbuf[wid][lane * 2] = make_float2(r0, r1);
    int half = lane >> 5, c = lane & 31;
    const float* rb = &rowbuf[wid][half * 64];
    const float* wr = &w2t[c][half * 64];
    float sum = 0.f;
#pragma unroll
    for (int k = 0; k < 64; k += 4) {
        float4 rv = *(const float4*)(rb + k);
        float4 wv = *(const float4*)(wr + k);
        sum = fmaf(rv.x, wv.x, sum);
        sum = fmaf(rv.y, wv.y, sum);
        sum = fmaf(rv.z, wv.z, sum);
        sum = fmaf(rv.w, wv.w, sum);
    }
    sum += __shfl_xor(sum, 32);
    if (valid && half == 0) H2b[(size_t)dst * 32 + c] = f2bf(sum);

    // fused score2: head = c>>3
    float v = sum * att2s[c];
    v += __shfl_xor(v, 1);
    v += __shfl_xor(v, 2);
    v += __shfl_xor(v, 4);
    if (valid && half == 0 && (c & 7) == 0)
        S2[dst * 4 + (c >> 3)] = 1.f / (1.f + __expf(-v));
}

// ---------------- conv2: 16 lanes/dst (uint = 2ch), 4 dsts/wave ----------

__global__ __launch_bounds__(256) void conv2_k(const uint* __restrict__ H2u,
                                               const float* __restrict__ S,
                                               const int* __restrict__ rowstart,
                                               const ushort* __restrict__ csrc,
                                               const float* __restrict__ b2,
                                               float* __restrict__ Out, int n) {
    int gtid = blockIdx.x * blockDim.x + threadIdx.x;
    int wave = gtid >> 6;
    int lane = threadIdx.x & 63;
    int q = lane >> 4;            // quarter -> dst
    int c2 = lane & 15;           // uint index: channels 2c2, 2c2+1
    int dst = wave * 4 + q;
    if (dst >= n) return;
    int hd = c2 >> 2;
    float si = S[dst * 4 + hd];
    float omsi = 1.f - si;
    int rs = rowstart[dst], re = rowstart[dst + 1];

    float z0 = 0.f, z1 = 0.f, z2 = 0.f, z3 = 0.f;
    float x0 = 0.f, x1 = 0.f, x2 = 0.f, x3 = 0.f;
    float y0 = 0.f, y1 = 0.f, y2 = 0.f, y3 = 0.f;
    int i = rs;
    for (; i + 3 < re; i += 4) {
        int s0 = csrc[i], s1 = csrc[i + 1], s2 = csrc[i + 2], s3 = csrc[i + 3];
        float sj0 = S[s0 * 4 + hd], sj1 = S[s1 * 4 + hd];
        float sj2 = S[s2 * 4 + hd], sj3 = S[s3 * 4 + hd];
        uint u0 = H2u[(size_t)s0 * 16 + c2];
        uint u1 = H2u[(size_t)s1 * 16 + c2];
        uint u2 = H2u[(size_t)s2 * 16 + c2];
        uint u3 = H2u[(size_t)s3 * 16 + c2];
        float w0 = __expf(fmaf(si, sj0, omsi * (1.f - sj0)));
        float w1 = __expf(fmaf(si, sj1, omsi * (1.f - sj1)));
        float w2 = __expf(fmaf(si, sj2, omsi * (1.f - sj2)));
        float w3 = __expf(fmaf(si, sj3, omsi * (1.f - sj3)));
        z0 += w0; z1 += w1; z2 += w2; z3 += w3;
        x0 = fmaf(w0, bf_lo(u0), x0); x1 = fmaf(w1, bf_lo(u1), x1);
        x2 = fmaf(w2, bf_lo(u2), x2); x3 = fmaf(w3, bf_lo(u3), x3);
        y0 = fmaf(w0, bf_hi(u0), y0); y1 = fmaf(w1, bf_hi(u1), y1);
        y2 = fmaf(w2, bf_hi(u2), y2); y3 = fmaf(w3, bf_hi(u3), y3);
    }
    for (; i < re; ++i) {
        int s0 = csrc[i];
        float sj0 = S[s0 * 4 + hd];
        uint u0 = H2u[(size_t)s0 * 16 + c2];
        float w0 = __expf(fmaf(si, sj0, omsi * (1.f - sj0)));
        z0 += w0;
        x0 = fmaf(w0, bf_lo(u0), x0);
        y0 = fmaf(w0, bf_hi(u0), y0);
    }
    float inv = 1.f / (((z0 + z1) + (z2 + z3)) + 1e-16f);
    float r0 = ((x0 + x1) + (x2 + x3)) * inv;
    float r1 = ((y0 + y1) + (y2 + y3)) * inv;
    // head-mean: lanes c2, c2^4, c2^8, c2^12 hold the 4 heads of channel pair
    r0 += __shfl_xor(r0, 4, 16); r0 += __shfl_xor(r0, 8, 16);
    r1 += __shfl_xor(r1, 4, 16); r1 += __shfl_xor(r1, 8, 16);
    if (c2 < 4) {
        float2 o = make_float2(r0 * 0.25f + b2[2 * c2],
                               r1 * 0.25f + b2[2 * c2 + 1]);
        *(float2*)(Out + (size_t)dst * 8 + 2 * c2) = o;
    }
}

// ---------------- launcher ----------------

static inline size_t align16(size_t x) { return (x + 15) & ~(size_t)15; }

extern "C" void kernel_launch(void* const* d_in, const int* in_sizes, int n_in,
                              void* d_out, int out_size, void* d_ws, size_t ws_size,
                              hipStream_t stream) {
    const float* x    = (const float*)d_in[0];
    const int*   edge = (const int*)d_in[1];
    const float* W1   = (const float*)d_in[2];
    const float* att1 = (const float*)d_in[3];
    const float* b1   = (const float*)d_in[4];
    const float* W2   = (const float*)d_in[5];
    const float* att2 = (const float*)d_in[6];
    const float* b2   = (const float*)d_in[7];

    int N  = in_sizes[0] / 256;
    int E  = in_sizes[1] / 2;
    int ET = E + N;
    int NB = (N + 1023) / 1024;
    const int* srcA = edge;
    const int* dstA = edge + E;

    char* ws = (char*)d_ws;
    uint*  h1b  = (uint*)ws;   ws += align16((size_t)N * 64 * sizeof(uint));   // bf16 x128
    ushort* h2b = (ushort*)ws; ws += align16((size_t)N * 32 * sizeof(ushort)); // bf16 x32
    float* s1   = (float*)ws;  ws += align16((size_t)N * 4 * sizeof(float));
    float* s2   = (float*)ws;  ws += align16((size_t)N * 4 * sizeof(float));
    int* rowstart = (int*)ws;  ws += align16((size_t)(N + 1) * sizeof(int));
    int* deg      = (int*)ws;  ws += align16((size_t)N * sizeof(int));
    ushort* csrc  = (ushort*)ws; ws += align16((size_t)ET * sizeof(ushort));
    ushort* epos  = (ushort*)ws; ws += align16((size_t)ET * sizeof(ushort));
    int* bsum     = (int*)ws;  ws += align16((size_t)NB * sizeof(int));
    int* boff     = (int*)ws;  ws += align16((size_t)NB * sizeof(int));
    ushort* w1t   = (ushort*)ws; ws += align16((size_t)256 * 128 * sizeof(ushort));

    hipMemsetAsync(deg, 0, (size_t)N * sizeof(int), stream);

    int eb = (ET + 255) / 256;
    count_pos_k<<<eb, 256, 0, stream>>>(dstA, E, ET, deg, epos);
    scan_a_k<<<NB, 256, 0, stream>>>(deg, N, rowstart, bsum);
    scan_b_k<<<1, 256, 0, stream>>>(bsum, NB, boff, rowstart + N);
    scan_c_k<<<(N + 255) / 256, 256, 0, stream>>>(rowstart, boff, N);
    scatter_k<<<eb, 256, 0, stream>>>(srcA, dstA, E, ET, rowstart, epos, csrc);

    prep_wt_k<<<(256 * 128 + 255) / 256, 256, 0, stream>>>(W1, w1t);
    gemm1_k<<<(N + 127) / 128, 256, 0, stream>>>(x, w1t, att1, h1b, s1, N);
    conv1_k<<<(N + 7) / 8, 512, 0, stream>>>(h1b, s1, rowstart, csrc, b1, W2, att2,
                                             h2b, s2, N);
    int waves2 = (N + 3) / 4;
    conv2_k<<<(waves2 * 64 + 255) / 256, 256, 0, stream>>>((const uint*)h2b, s2,
                                                           rowstart, csrc, b2,
                                                           (float*)d_out, N);
}

// Round 8
// 154.767 us; speedup vs baseline: 3.3400x; 1.0387x over previous
//
#include <hip/hip_runtime.h>
#include <math.h>

// N=50000, E=800000, IN_DIM=256, H=4, HID=32 (conv1), OUT=8 (conv2).
// HDIM1=128, HDIM2=32.
//
// Softmax logit = si*sj + (1-si)(1-sj) in (0,1) -> exp can't overflow ->
// segment-max pass omitted (single-pass softmax).
//
// H1/H2 stored bf16 (f32 math). GEMM1 = mfma_f32_16x16x32_bf16 with fused
// score1. conv1 (persistent, wave-per-dst strided): phase-A per-edge weights
// (1 exp per edge-head, lanes=edges, chunk=64) into LDS + src ids kept in
// lane regs (readlane in B); phase-B lean gather unroll 8; fused gemm2 +
// score2. conv2 (persistent): wave per dst, 4 edge-slots x 16 ch-lanes.
// CSR: ushort csrc, atomic-free scatter.

typedef __attribute__((ext_vector_type(8))) short bf16x8;
typedef __attribute__((ext_vector_type(4))) float f32x4;

__device__ inline ushort f2bf(float f) {            // RNE f32->bf16
    uint u = __float_as_uint(f);
    return (ushort)((u + 0x7fffu + ((u >> 16) & 1u)) >> 16);
}
__device__ inline float bf_lo(uint u) { return __uint_as_float(u << 16); }
__device__ inline float bf_hi(uint u) { return __uint_as_float(u & 0xffff0000u); }

// ---------------- CSR build ----------------

__global__ void count_pos_k(const int* __restrict__ dstA, int E, int ET,
                            int* __restrict__ deg, ushort* __restrict__ epos) {
    int e = blockIdx.x * blockDim.x + threadIdx.x;
    if (e >= ET) return;
    int d = (e < E) ? dstA[e] : (e - E);   // self-loop edges appended
    epos[e] = (ushort)atomicAdd(&deg[d], 1);
}

__global__ __launch_bounds__(256) void scan_a_k(const int* __restrict__ deg, int n,
                                                int* __restrict__ rowstart,
                                                int* __restrict__ bsum) {
    __shared__ int ts[256];
    int t = threadIdx.x;
    int idx = blockIdx.x * 1024 + t * 4;
    int4 v = make_int4(0, 0, 0, 0);
    if (idx + 3 < n) {
        v = *(const int4*)(deg + idx);
    } else {
        if (idx < n)     v.x = deg[idx];
        if (idx + 1 < n) v.y = deg[idx + 1];
        if (idx + 2 < n) v.z = deg[idx + 2];
        if (idx + 3 < n) v.w = deg[idx + 3];
    }
    int s = v.x + v.y + v.z + v.w;
    ts[t] = s;
    __syncthreads();
#pragma unroll
    for (int off = 1; off < 256; off <<= 1) {
        int u = (t >= off) ? ts[t - off] : 0;
        __syncthreads();
        ts[t] += u;
        __syncthreads();
    }
    int excl = ts[t] - s;
    int p1 = excl + v.x, p2 = p1 + v.y, p3 = p2 + v.z;
    if (idx < n)     rowstart[idx]     = excl;
    if (idx + 1 < n) rowstart[idx + 1] = p1;
    if (idx + 2 < n) rowstart[idx + 2] = p2;
    if (idx + 3 < n) rowstart[idx + 3] = p3;
    if (t == 255) bsum[blockIdx.x] = ts[255];
}

__global__ __launch_bounds__(256) void scan_b_k(const int* __restrict__ bsum, int nb,
                                                int* __restrict__ boff,
                                                int* __restrict__ totalp) {
    __shared__ int ts[256];
    int t = threadIdx.x;
    int v = (t < nb) ? bsum[t] : 0;
    ts[t] = v;
    __syncthreads();
#pragma unroll
    for (int off = 1; off < 256; off <<= 1) {
        int u = (t >= off) ? ts[t - off] : 0;
        __syncthreads();
        ts[t] += u;
        __syncthreads();
    }
    if (t < nb) boff[t] = ts[t] - v;
    if (t == nb - 1) *totalp = ts[t];
}

__global__ void scan_c_k(int* __restrict__ rowstart, const int* __restrict__ boff,
                         int n) {
    int i = blockIdx.x * blockDim.x + threadIdx.x;
    if (i < n) rowstart[i] += boff[i >> 10];
}

__global__ void scatter_k(const int* __restrict__ srcA, const int* __restrict__ dstA,
                          int E, int ET, const int* __restrict__ rowstart,
                          const ushort* __restrict__ epos,
                          ushort* __restrict__ csrc) {
    int e = blockIdx.x * blockDim.x + threadIdx.x;
    if (e >= ET) return;
    int d, s;
    if (e < E) { d = dstA[e]; s = srcA[e]; } else { d = e - E; s = e - E; }
    csrc[rowstart[d] + epos[e]] = (ushort)s;
}

// ---------------- W1 transpose+cvt: Wt[col][k] bf16 ----------------

__global__ void prep_wt_k(const float* __restrict__ W, ushort* __restrict__ Wt) {
    int idx = blockIdx.x * blockDim.x + threadIdx.x;
    if (idx >= 256 * 128) return;
    int k = idx >> 7, col = idx & 127;
    Wt[col * 256 + k] = f2bf(W[idx]);
}

// ---------------- GEMM1 (MFMA) + fused score1 ----------------

__global__ __launch_bounds__(256) void gemm1_k(const float* __restrict__ X,
                                               const ushort* __restrict__ Wt,
                                               const float* __restrict__ ATT1,
                                               uint* __restrict__ H1b,
                                               float* __restrict__ S1, int n) {
    __shared__ __align__(16) ushort Alds[4][128][8];
    __shared__ __align__(16) ushort Blds[4][128][8];
    __shared__ float att1s[128];
    int tid = threadIdx.x;
    int wid = tid >> 6;
    int lane = tid & 63;
    int g = lane >> 4;
    int lr = lane & 15;
    int brow = blockIdx.x * 128;
    if (tid < 128) att1s[tid] = ATT1[tid];

    f32x4 acc[2][8];
#pragma unroll
    for (int rt = 0; rt < 2; ++rt)
#pragma unroll
        for (int ct = 0; ct < 8; ++ct) acc[rt][ct] = (f32x4){0.f, 0.f, 0.f, 0.f};

    for (int k0 = 0; k0 < 256; k0 += 32) {
#pragma unroll
        for (int rep = 0; rep < 2; ++rep) {
            int idx = tid + rep * 256;
            int r = idx >> 2, koct = idx & 3;
            int gr = brow + r;
            float4 a0, a1;
            if (gr < n) {
                const float* p = X + (size_t)gr * 256 + k0 + koct * 8;
                a0 = *(const float4*)p;
                a1 = *(const float4*)(p + 4);
            } else {
                a0 = a1 = make_float4(0.f, 0.f, 0.f, 0.f);
            }
            uint4 pk;
            pk.x = (uint)f2bf(a0.x) | ((uint)f2bf(a0.y) << 16);
            pk.y = (uint)f2bf(a0.z) | ((uint)f2bf(a0.w) << 16);
            pk.z = (uint)f2bf(a1.x) | ((uint)f2bf(a1.y) << 16);
            pk.w = (uint)f2bf(a1.z) | ((uint)f2bf(a1.w) << 16);
            *(uint4*)&Alds[koct][r][0] = pk;
        }
#pragma unroll
        for (int rep = 0; rep < 2; ++rep) {
            int idx = tid + rep * 256;
            int col = idx & 127, koct = idx >> 7;
            *(uint4*)&Blds[koct][col][0] =
                *(const uint4*)(Wt + (size_t)col * 256 + k0 + koct * 8);
        }
        __syncthreads();
        bf16x8 xf0 = *(bf16x8*)&Alds[g][wid * 32 + lr][0];
        bf16x8 xf1 = *(bf16x8*)&Alds[g][wid * 32 + 16 + lr][0];
#pragma unroll
        for (int ct = 0; ct < 8; ++ct) {
            bf16x8 wf = *(bf16x8*)&Blds[g][ct * 16 + lr][0];
            acc[0][ct] = __builtin_amdgcn_mfma_f32_16x16x32_bf16(wf, xf0, acc[0][ct], 0, 0, 0);
            acc[1][ct] = __builtin_amdgcn_mfma_f32_16x16x32_bf16(wf, xf1, acc[1][ct], 0, 0, 0);
        }
        __syncthreads();
    }
#pragma unroll
    for (int rt = 0; rt < 2; ++rt) {
        int row = brow + wid * 32 + rt * 16 + lr;
        if (row < n) {
#pragma unroll
            for (int ct = 0; ct < 8; ++ct) {
                uint lo = (uint)f2bf(acc[rt][ct][0]) | ((uint)f2bf(acc[rt][ct][1]) << 16);
                uint hi = (uint)f2bf(acc[rt][ct][2]) | ((uint)f2bf(acc[rt][ct][3]) << 16);
                *(uint2*)(H1b + (size_t)row * 64 + ct * 8 + g * 2) = make_uint2(lo, hi);
            }
        }
        float sc[4] = {0.f, 0.f, 0.f, 0.f};
#pragma unroll
        for (int ct = 0; ct < 8; ++ct) {
            int base = ct * 16 + g * 4;
#pragma unroll
            for (int j = 0; j < 4; ++j)
                sc[ct >> 1] = fmaf(acc[rt][ct][j], att1s[base + j], sc[ct >> 1]);
        }
#pragma unroll
        for (int h = 0; h < 4; ++h) {
            sc[h] += __shfl_xor(sc[h], 16);
            sc[h] += __shfl_xor(sc[h], 32);
        }
        if (g == 0 && row < n) {
            float4 sv;
            sv.x = 1.f / (1.f + __expf(-sc[0]));
            sv.y = 1.f / (1.f + __expf(-sc[1]));
            sv.z = 1.f / (1.f + __expf(-sc[2]));
            sv.w = 1.f / (1.f + __expf(-sc[3]));
            *(float4*)(S1 + (size_t)row * 4) = sv;
        }
    }
}

// ---------------- conv1 + fused gemm2 + score2 (persistent) ----------------

__global__ __launch_bounds__(512, 8) void conv1_k(const uint* __restrict__ H1b,
                                                  const float* __restrict__ S1,
                                                  const int* __restrict__ rowstart,
                                                  const ushort* __restrict__ csrc,
                                                  const float* __restrict__ b1,
                                                  const float* __restrict__ W2,
                                                  const float* __restrict__ ATT2,
                                                  ushort* __restrict__ H2b,
                                                  float* __restrict__ S2,
                                                  int n, int nwaves) {
    __shared__ float w2t[32][132];     // transposed W2, padded (16.9 KB)
    __shared__ float rowbuf[8][128];   // 4 KB
    __shared__ float wbuf[8][64][4];   // 8 KB  per-edge weights (chunk of 64)
    __shared__ float att2s[32];
    int tid = threadIdx.x;
    for (int idx = tid; idx < 4096; idx += 512) {
        int k = idx >> 5, c = idx & 31;
        w2t[c][k] = W2[idx];
    }
    if (tid < 32) att2s[tid] = ATT2[tid];
    __syncthreads();

    int wid = tid >> 6;
    int lane = tid & 63;
    int hd = lane >> 4;
    int half = lane >> 5, cc2 = lane & 31;
    int gwave = blockIdx.x * 8 + wid;
    float2 b1v = *(const float2*)(b1 + lane * 2);

    for (int dst = gwave; dst < n; dst += nwaves) {
        int rs = rowstart[dst], re = rowstart[dst + 1];
        float4 si4 = *(const float4*)(S1 + (size_t)dst * 4);
        float z0 = 0.f, z1 = 0.f, z2 = 0.f, z3 = 0.f;
        float x0 = 0.f, x1 = 0.f, x2 = 0.f, x3 = 0.f;
        float y0 = 0.f, y1 = 0.f, y2 = 0.f, y3 = 0.f;

        for (int cb = rs; cb < re; cb += 64) {
            int cc = min(64, re - cb);
            int sv = 0;
            // ---- phase A: per-edge weights (all 4 heads), lanes = edges ----
            if (lane < cc) {
                sv = csrc[cb + lane];
                float4 sj = *(const float4*)(S1 + (size_t)sv * 4);
                float w0 = __expf(fmaf(si4.x, sj.x, (1.f - si4.x) * (1.f - sj.x)));
                float w1 = __expf(fmaf(si4.y, sj.y, (1.f - si4.y) * (1.f - sj.y)));
                float w2 = __expf(fmaf(si4.z, sj.z, (1.f - si4.z) * (1.f - sj.z)));
                float w3 = __expf(fmaf(si4.w, sj.w, (1.f - si4.w) * (1.f - sj.w)));
                *(float4*)&wbuf[wid][lane][0] = make_float4(w0, w1, w2, w3);
            }
            asm volatile("s_waitcnt lgkmcnt(0)" ::: "memory");
            // ---- phase B: channel gather, src ids via readlane ----
            int e = 0;
            for (; e + 7 < cc; e += 8) {
                int sA = __builtin_amdgcn_readlane(sv, e);
                int sB = __builtin_amdgcn_readlane(sv, e + 1);
                int sC = __builtin_amdgcn_readlane(sv, e + 2);
                int sD = __builtin_amdgcn_readlane(sv, e + 3);
                int sE = __builtin_amdgcn_readlane(sv, e + 4);
                int sF = __builtin_amdgcn_readlane(sv, e + 5);
                int sG = __builtin_amdgcn_readlane(sv, e + 6);
                int sH = __builtin_amdgcn_readlane(sv, e + 7);
                float wA = wbuf[wid][e][hd],     wB = wbuf[wid][e + 1][hd];
                float wC = wbuf[wid][e + 2][hd], wD = wbuf[wid][e + 3][hd];
                float wE = wbuf[wid][e + 4][hd], wF = wbuf[wid][e + 5][hd];
                float wG = wbuf[wid][e + 6][hd], wH = wbuf[wid][e + 7][hd];
                uint uA = H1b[(size_t)sA * 64 + lane];
                uint uB = H1b[(size_t)sB * 64 + lane];
                uint uC = H1b[(size_t)sC * 64 + lane];
                uint uD = H1b[(size_t)sD * 64 + lane];
                uint uE = H1b[(size_t)sE * 64 + lane];
                uint uF = H1b[(size_t)sF * 64 + lane];
                uint uG = H1b[(size_t)sG * 64 + lane];
                uint uH = H1b[(size_t)sH * 64 + lane];
                z0 += wA + wE; z1 += wB + wF; z2 += wC + wG; z3 += wD + wH;
                x0 = fmaf(wA, bf_lo(uA), x0); x1 = fmaf(wB, bf_lo(uB), x1);
                x2 = fmaf(wC, bf_lo(uC), x2); x3 = fmaf(wD, bf_lo(uD), x3);
                x0 = fmaf(wE, bf_lo(uE), x0); x1 = fmaf(wF, bf_lo(uF), x1);
                x2 = fmaf(wG, bf_lo(uG), x2); x3 = fmaf(wH, bf_lo(uH), x3);
                y0 = fmaf(wA, bf_hi(uA), y0); y1 = fmaf(wB, bf_hi(uB), y1);
                y2 = fmaf(wC, bf_hi(uC), y2); y3 = fmaf(wD, bf_hi(uD), y3);
                y0 = fmaf(wE, bf_hi(uE), y0); y1 = fmaf(wF, bf_hi(uF), y1);
                y2 = fmaf(wG, bf_hi(uG), y2); y3 = fmaf(wH, bf_hi(uH), y3);
            }
            for (; e < cc; ++e) {
                int s = __builtin_amdgcn_readlane(sv, e);
                float w = wbuf[wid][e][hd];
                uint u = H1b[(size_t)s * 64 + lane];
                z0 += w;
                x0 = fmaf(w, bf_lo(u), x0);
                y0 = fmaf(w, bf_hi(u), y0);
            }
            asm volatile("" ::: "memory");
        }
        float inv = 1.f / ((z0 + z1) + (z2 + z3) + 1e-16f);
        float r0 = ((x0 + x1) + (x2 + x3)) * inv + b1v.x;
        float r1 = ((y0 + y1) + (y2 + y3)) * inv + b1v.y;
        r0 = (r0 > 0.f) ? r0 : (__expf(r0) - 1.f);   // ELU
        r1 = (r1 > 0.f) ? r1 : (__expf(r1) - 1.f);

        // fused gemm2: split-k across wave halves, float4 LDS reads
        *(float2*)&rowbuf[wid][lane * 2] = make_float2(r0, r1);
        asm volatile("s_waitcnt lgkmcnt(0)" ::: "memory");
        const float* rb = &rowbuf[wid][half * 64];
        const float* wr = &w2t[cc2][half * 64];
        float sum = 0.f;
#pragma unroll
        for (int k = 0; k < 64; k += 4) {
            float4 rv = *(const float4*)(rb + k);
            float4 wv = *(const float4*)(wr + k);
            sum = fmaf(rv.x, wv.x, sum);
            sum = fmaf(rv.y, wv.y, sum);
            sum = fmaf(rv.z, wv.z, sum);
            sum = fmaf(rv.w, wv.w, sum);
        }
        sum += __shfl_xor(sum, 32);
        if (half == 0) H2b[(size_t)dst * 32 + cc2] = f2bf(sum);

        // fused score2: head = cc2>>3
        float v = sum * att2s[cc2];
        v += __shfl_xor(v, 1);
        v += __shfl_xor(v, 2);
        v += __shfl_xor(v, 4);
        if (half == 0 && (cc2 & 7) == 0)
            S2[dst * 4 + (cc2 >> 3)] = 1.f / (1.f + __expf(-v));
    }
}

// ---------------- conv2 (persistent): wave per dst, 4 eslots x 16 ch -------

__global__ __launch_bounds__(256, 8) void conv2_k(const uint* __restrict__ H2u,
                                                  const float* __restrict__ S,
                                                  const int* __restrict__ rowstart,
                                                  const ushort* __restrict__ csrc,
                                                  const float* __restrict__ b2,
                                                  float* __restrict__ Out,
                                                  int n, int nwaves) {
    int gwave = (int)((blockIdx.x * blockDim.x + threadIdx.x) >> 6);
    int lane = threadIdx.x & 63;
    int eslot = lane >> 4;        // edge slot 0..3
    int c2 = lane & 15;           // uint index: channels 2c2, 2c2+1
    int hd = c2 >> 2;
    float2 b2v;
    b2v.x = b2[2 * (c2 & 3)];
    b2v.y = b2[2 * (c2 & 3) + 1];

    for (int dst = gwave; dst < n; dst += nwaves) {
        float si = S[dst * 4 + hd];
        float omsi = 1.f - si;
        int rs = rowstart[dst], re = rowstart[dst + 1];
        int cnt = re - rs;
        float z = 0.f, x = 0.f, y = 0.f;
        int i = eslot;
        for (; i + 4 < cnt; i += 8) {
            int s0 = csrc[rs + i];
            int s1 = csrc[rs + i + 4];
            float sj0 = S[s0 * 4 + hd];
            float sj1 = S[s1 * 4 + hd];
            uint u0 = H2u[(size_t)s0 * 16 + c2];
            uint u1 = H2u[(size_t)s1 * 16 + c2];
            float w0 = __expf(fmaf(si, sj0, omsi * (1.f - sj0)));
            float w1 = __expf(fmaf(si, sj1, omsi * (1.f - sj1)));
            z += w0 + w1;
            x = fmaf(w0, bf_lo(u0), x); x = fmaf(w1, bf_lo(u1), x);
            y = fmaf(w0, bf_hi(u0), y); y = fmaf(w1, bf_hi(u1), y);
        }
        if (i < cnt) {
            int s0 = csrc[rs + i];
            float sj0 = S[s0 * 4 + hd];
            uint u0 = H2u[(size_t)s0 * 16 + c2];
            float w0 = __expf(fmaf(si, sj0, omsi * (1.f - sj0)));
            z += w0;
            x = fmaf(w0, bf_lo(u0), x);
            y = fmaf(w0, bf_hi(u0), y);
        }
        // reduce across edge slots
        z += __shfl_xor(z, 16); z += __shfl_xor(z, 32);
        x += __shfl_xor(x, 16); x += __shfl_xor(x, 32);
        y += __shfl_xor(y, 16); y += __shfl_xor(y, 32);
        float inv = 1.f / (z + 1e-16f);
        float r0 = x * inv, r1 = y * inv;
        // head-mean within 16-lane group
        r0 += __shfl_xor(r0, 4, 16); r0 += __shfl_xor(r0, 8, 16);
        r1 += __shfl_xor(r1, 4, 16); r1 += __shfl_xor(r1, 8, 16);
        if (eslot == 0 && c2 < 4) {
            float2 o = make_float2(r0 * 0.25f + b2v.x, r1 * 0.25f + b2v.y);
            *(float2*)(Out + (size_t)dst * 8 + 2 * c2) = o;
        }
    }
}

// ---------------- launcher ----------------

static inline size_t align16(size_t x) { return (x + 15) & ~(size_t)15; }

extern "C" void kernel_launch(void* const* d_in, const int* in_sizes, int n_in,
                              void* d_out, int out_size, void* d_ws, size_t ws_size,
                              hipStream_t stream) {
    const float* x    = (const float*)d_in[0];
    const int*   edge = (const int*)d_in[1];
    const float* W1   = (const float*)d_in[2];
    const float* att1 = (const float*)d_in[3];
    const float* b1   = (const float*)d_in[4];
    const float* W2   = (const float*)d_in[5];
    const float* att2 = (const float*)d_in[6];
    const float* b2   = (const float*)d_in[7];

    int N  = in_sizes[0] / 256;
    int E  = in_sizes[1] / 2;
    int ET = E + N;
    int NB = (N + 1023) / 1024;
    const int* srcA = edge;
    const int* dstA = edge + E;

    char* ws = (char*)d_ws;
    uint*  h1b  = (uint*)ws;   ws += align16((size_t)N * 64 * sizeof(uint));   // bf16 x128
    ushort* h2b = (ushort*)ws; ws += align16((size_t)N * 32 * sizeof(ushort)); // bf16 x32
    float* s1   = (float*)ws;  ws += align16((size_t)N * 4 * sizeof(float));
    float* s2   = (float*)ws;  ws += align16((size_t)N * 4 * sizeof(float));
    int* rowstart = (int*)ws;  ws += align16((size_t)(N + 1) * sizeof(int));
    int* deg      = (int*)ws;  ws += align16((size_t)N * sizeof(int));
    ushort* csrc  = (ushort*)ws; ws += align16((size_t)ET * sizeof(ushort));
    ushort* epos  = (ushort*)ws; ws += align16((size_t)ET * sizeof(ushort));
    int* bsum     = (int*)ws;  ws += align16((size_t)NB * sizeof(int));
    int* boff     = (int*)ws;  ws += align16((size_t)NB * sizeof(int));
    ushort* w1t   = (ushort*)ws; ws += align16((size_t)256 * 128 * sizeof(ushort));

    hipMemsetAsync(deg, 0, (size_t)N * sizeof(int), stream);

    int eb = (ET + 255) / 256;
    count_pos_k<<<eb, 256, 0, stream>>>(dstA, E, ET, deg, epos);
    scan_a_k<<<NB, 256, 0, stream>>>(deg, N, rowstart, bsum);
    scan_b_k<<<1, 256, 0, stream>>>(bsum, NB, boff, rowstart + N);
    scan_c_k<<<(N + 255) / 256, 256, 0, stream>>>(rowstart, boff, N);
    scatter_k<<<eb, 256, 0, stream>>>(srcA, dstA, E, ET, rowstart, epos, csrc);

    prep_wt_k<<<(256 * 128 + 255) / 256, 256, 0, stream>>>(W1, w1t);
    gemm1_k<<<(N + 127) / 128, 256, 0, stream>>>(x, w1t, att1, h1b, s1, N);

    int c1_blocks = 1024;
    if (c1_blocks > (N + 7) / 8) c1_blocks = (N + 7) / 8;
    int c1_waves = c1_blocks * 8;
    conv1_k<<<c1_blocks, 512, 0, stream>>>(h1b, s1, rowstart, csrc, b1, W2, att2,
                                           h2b, s2, N, c1_waves);

    int c2_blocks = 2048;
    if (c2_blocks > (N + 3) / 4) c2_blocks = (N + 3) / 4;
    int c2_waves = c2_blocks * 4;
    conv2_k<<<c2_blocks, 256, 0, stream>>>((const uint*)h2b, s2, rowstart, csrc, b2,
                                           (float*)d_out, N, c2_waves);
}